// Round 3
// baseline (884.322 us; speedup 1.0000x reference)
//
#include <hip/hip_runtime.h>
#include <hip/hip_fp16.h>
#include <math.h>

// Graph TransformerConv ×2 on MI355X.
// N=100000 nodes, E=800000 edges, D=64, H=4 heads, C=64 (H*C=256).
//
// R2: suspect R1's abort was a d_ws overflow (needed ~366 MB, never checked
// ws_size). Now: Q/K/V stored fp16 (halves footprint), layer-1 hidden state
// lives in d_out (layer-2 GEMMs consume it before attn overwrites), total
// workspace ~184 MB, and a ws_size guard that makes "workspace too small"
// show up as absmax-fail (zeros) instead of a GPU fault.

struct alignas(8) h4 { __half x, y, z, w; };

// ---------------- zeroing ----------------
__global__ void k_zero2(int* __restrict__ a, int* __restrict__ b, int n) {
    int i = blockIdx.x * 256 + threadIdx.x;
    if (i < n) { a[i] = 0; b[i] = 0; }
}

// ---------------- CSR build ----------------
__global__ void k_hist(const int* __restrict__ dst, int E, int* __restrict__ counts) {
    int e = blockIdx.x * 256 + threadIdx.x;
    if (e < E) atomicAdd(&counts[dst[e]], 1);
}

#define SCAN_B 256
#define SCAN_CHUNK 2048
__global__ void k_scan1(const int* __restrict__ counts, int n,
                        int* __restrict__ offs, int* __restrict__ bsums) {
    __shared__ int lds[SCAN_B];
    int b = blockIdx.x, tid = threadIdx.x;
    int base = b * SCAN_CHUNK + tid * 8;
    int v[8]; int s = 0;
#pragma unroll
    for (int i = 0; i < 8; ++i) { int idx = base + i; int c = (idx < n) ? counts[idx] : 0; v[i] = s; s += c; }
    lds[tid] = s;
    for (int off = 1; off < SCAN_B; off <<= 1) {
        __syncthreads();
        int x = (tid >= off) ? lds[tid - off] : 0;
        __syncthreads();
        lds[tid] += x;
    }
    __syncthreads();
    int texcl = lds[tid] - s;
#pragma unroll
    for (int i = 0; i < 8; ++i) { int idx = base + i; if (idx < n) offs[idx] = texcl + v[i]; }
    if (tid == SCAN_B - 1) bsums[b] = lds[tid];
}

__global__ void k_scan2(int* bsums, int nb) {
    if (threadIdx.x == 0 && blockIdx.x == 0) {
        int s = 0;
        for (int i = 0; i < nb; ++i) { int c = bsums[i]; bsums[i] = s; s += c; }
    }
}

__global__ void k_scan3(int* __restrict__ offs, const int* __restrict__ bsums, int n, int total) {
    int idx = blockIdx.x * 256 + threadIdx.x;
    if (idx < n) offs[idx] += bsums[idx / SCAN_CHUNK];
    if (idx == 0) offs[n] = total;
}

__global__ void k_scatter(const int* __restrict__ src, const int* __restrict__ dst, int E,
                          const int* __restrict__ offs, int* __restrict__ cursor,
                          int* __restrict__ csr_src) {
    int e = blockIdx.x * 256 + threadIdx.x;
    if (e < E) {
        int d = dst[e];
        int p = offs[d] + atomicAdd(&cursor[d], 1);
        csr_src[p] = src[e];
    }
}

// ---------------- GEMM: [nrows,64] @ [64,256] + b, x3 matrices, fp16 out ----
// LDS: only the 32x64 X tile (8 KB). W rows read from global (64 KB, L1/L2).
__global__ __launch_bounds__(256) void k_gemm_qkv(
    const float* __restrict__ X, int nrows,
    const float* __restrict__ Wq, const float* __restrict__ bq,
    const float* __restrict__ Wk, const float* __restrict__ bk,
    const float* __restrict__ Wv, const float* __restrict__ bv,
    h4* __restrict__ Qo, h4* __restrict__ Ko, h4* __restrict__ Vo)
{
    __shared__ float xt[32 * 64];    // 8 KB
    const float* W; const float* bias; h4* O;
    if (blockIdx.y == 0)      { W = Wq; bias = bq; O = Qo; }
    else if (blockIdx.y == 1) { W = Wk; bias = bk; O = Ko; }
    else                      { W = Wv; bias = bv; O = Vo; }
    int tid = threadIdx.x;
    int r0 = blockIdx.x * 32;
    for (int i = tid; i < 512; i += 256) {
        int row = r0 + (i >> 4);
        ((float4*)xt)[i] = (row < nrows) ? ((const float4*)X)[row * 16 + (i & 15)]
                                         : make_float4(0.f, 0.f, 0.f, 0.f);
    }
    __syncthreads();
    int wave = tid >> 6, lane = tid & 63;
    int rbase = wave * 8;
    float4 acc[8];
#pragma unroll
    for (int r = 0; r < 8; ++r) acc[r] = make_float4(0.f, 0.f, 0.f, 0.f);
#pragma unroll 4
    for (int j = 0; j < 64; ++j) {
        float4 w4 = ((const float4*)(W + j * 256))[lane];
#pragma unroll
        for (int r = 0; r < 8; ++r) {
            float xj = xt[(rbase + r) * 64 + j];
            acc[r].x += xj * w4.x; acc[r].y += xj * w4.y;
            acc[r].z += xj * w4.z; acc[r].w += xj * w4.w;
        }
    }
    float4 b4 = ((const float4*)bias)[lane];
#pragma unroll
    for (int r = 0; r < 8; ++r) {
        int row = r0 + rbase + r;
        if (row < nrows) {
            h4 o;
            o.x = __float2half_rn(acc[r].x + b4.x);
            o.y = __float2half_rn(acc[r].y + b4.y);
            o.z = __float2half_rn(acc[r].z + b4.z);
            o.w = __float2half_rn(acc[r].w + b4.w);
            O[(size_t)row * 64 + lane] = o;
        }
    }
}

// ---------------- GEMM: [nrows,64] @ [64,64] + b (skip path, fp32 out) ------
__global__ __launch_bounds__(256) void k_gemm_s(
    const float* __restrict__ X, int nrows,
    const float* __restrict__ W, const float* __restrict__ bias,
    float* __restrict__ O)
{
    __shared__ float Wl[64 * 64];    // 16 KB
    __shared__ float xt[32 * 64];    // 8 KB
    int tid = threadIdx.x;
    for (int i = tid; i < 1024; i += 256) ((float4*)Wl)[i] = ((const float4*)W)[i];
    int r0 = blockIdx.x * 32;
    for (int i = tid; i < 512; i += 256) {
        int row = r0 + (i >> 4);
        ((float4*)xt)[i] = (row < nrows) ? ((const float4*)X)[row * 16 + (i & 15)]
                                         : make_float4(0.f, 0.f, 0.f, 0.f);
    }
    __syncthreads();
    int wave = tid >> 6, lane = tid & 63;
    int rbase = wave * 8;
    float acc[8];
#pragma unroll
    for (int r = 0; r < 8; ++r) acc[r] = 0.f;
#pragma unroll
    for (int j = 0; j < 64; ++j) {
        float w = Wl[j * 64 + lane];
#pragma unroll
        for (int r = 0; r < 8; ++r) acc[r] += xt[(rbase + r) * 64 + j] * w;
    }
    float bv = bias[lane];
#pragma unroll
    for (int r = 0; r < 8; ++r) {
        int row = r0 + rbase + r;
        if (row < nrows) O[row * 64 + lane] = acc[r] + bv;
    }
}

// ---------------- Attention: one wave per destination node ----------------
__global__ __launch_bounds__(256) void k_attn(
    const h4* __restrict__ Q, const h4* __restrict__ K,
    const h4* __restrict__ V, const float* __restrict__ S,
    const int* __restrict__ offs, const int* __restrict__ csr_src,
    float* __restrict__ out, int n, int relu)
{
    int node = blockIdx.x * 4 + (threadIdx.x >> 6);
    if (node >= n) return;
    int lane = threadIdx.x & 63;
    int li = lane & 15;
    h4 qh = Q[(size_t)node * 64 + lane];
    float4 q4 = make_float4(__half2float(qh.x), __half2float(qh.y),
                            __half2float(qh.z), __half2float(qh.w));
    int beg = offs[node], end = offs[node + 1];
    float m = -3.4e38f, l = 0.f;
    float4 acc = make_float4(0.f, 0.f, 0.f, 0.f);
    for (int i = beg; i < end; ++i) {
        int s = csr_src[i];
        h4 kh = K[(size_t)s * 64 + lane];
        h4 vh = V[(size_t)s * 64 + lane];
        float d = q4.x * __half2float(kh.x) + q4.y * __half2float(kh.y)
                + q4.z * __half2float(kh.z) + q4.w * __half2float(kh.w);
        d += __shfl_xor(d, 1); d += __shfl_xor(d, 2);
        d += __shfl_xor(d, 4); d += __shfl_xor(d, 8);   // per-head dot (16-lane groups)
        float alpha = d * 0.125f;                        // / sqrt(64)
        float nm = fmaxf(m, alpha);
        float sc = __expf(m - nm);
        float w  = __expf(alpha - nm);
        l = l * sc + w;
        m = nm;
        acc.x = acc.x * sc + __half2float(vh.x) * w;
        acc.y = acc.y * sc + __half2float(vh.y) * w;
        acc.z = acc.z * sc + __half2float(vh.z) * w;
        acc.w = acc.w * sc + __half2float(vh.w) * w;
    }
    float inv = 1.f / (l + 1e-16f);
    float4 r = make_float4(acc.x * inv, acc.y * inv, acc.z * inv, acc.w * inv);
    // sum across heads (quarters), then mean
    r.x += __shfl_xor(r.x, 16); r.x += __shfl_xor(r.x, 32);
    r.y += __shfl_xor(r.y, 16); r.y += __shfl_xor(r.y, 32);
    r.z += __shfl_xor(r.z, 16); r.z += __shfl_xor(r.z, 32);
    r.w += __shfl_xor(r.w, 16); r.w += __shfl_xor(r.w, 32);
    float4 s4 = *(const float4*)(S + (size_t)node * 64 + li * 4);
    r.x = r.x * 0.25f + s4.x; r.y = r.y * 0.25f + s4.y;
    r.z = r.z * 0.25f + s4.z; r.w = r.w * 0.25f + s4.w;
    if (relu) {
        r.x = fmaxf(r.x, 0.f); r.y = fmaxf(r.y, 0.f);
        r.z = fmaxf(r.z, 0.f); r.w = fmaxf(r.w, 0.f);
    }
    if (lane < 16) *(float4*)(out + (size_t)node * 64 + li * 4) = r;
}

extern "C" void kernel_launch(void* const* d_in, const int* in_sizes, int n_in,
                              void* d_out, int out_size, void* d_ws, size_t ws_size,
                              hipStream_t stream)
{
    const float* x  = (const float*)d_in[0];
    const int*   ei = (const int*)d_in[1];
    int N = in_sizes[0] / 64;
    int E = in_sizes[1] / 2;
    const int* srcp = ei;
    const int* dstp = ei + E;
    const float* Wq1 = (const float*)d_in[2],  *bq1 = (const float*)d_in[3];
    const float* Wk1 = (const float*)d_in[4],  *bk1 = (const float*)d_in[5];
    const float* Wv1 = (const float*)d_in[6],  *bv1 = (const float*)d_in[7];
    const float* Ws1 = (const float*)d_in[8],  *bs1 = (const float*)d_in[9];
    const float* Wq2 = (const float*)d_in[10], *bq2 = (const float*)d_in[11];
    const float* Wk2 = (const float*)d_in[12], *bk2 = (const float*)d_in[13];
    const float* Wv2 = (const float*)d_in[14], *bv2 = (const float*)d_in[15];
    const float* Ws2 = (const float*)d_in[16], *bs2 = (const float*)d_in[17];
    float* out = (float*)d_out;

    // workspace layout (~184 MB)
    char* ws = (char*)d_ws;
    size_t off = 0;
    auto alloc = [&](size_t bytes) -> void* {
        void* p = ws + off;
        off = (off + bytes + 255) & ~(size_t)255;
        return p;
    };
    h4* Q       = (h4*)alloc((size_t)N * 256 * 2);
    h4* K       = (h4*)alloc((size_t)N * 256 * 2);
    h4* V       = (h4*)alloc((size_t)N * 256 * 2);
    float* S    = (float*)alloc((size_t)N * 64 * 4);
    int* counts = (int*)alloc((size_t)N * 4);
    int* cursor = (int*)alloc((size_t)N * 4);
    int* offs   = (int*)alloc((size_t)(N + 1) * 4);
    int* bsums  = (int*)alloc(1024 * 4);
    int* csr    = (int*)alloc((size_t)E * 4);
    (void)n_in; (void)out_size;

    // Guard: if the workspace is too small, do nothing -> harness reports
    // absmax-fail (zeros) instead of a GPU memory fault. Diagnostic signal.
    if (off > ws_size) return;

    int ebl = (E + 255) / 256;
    int nb_scan = (N + SCAN_CHUNK - 1) / SCAN_CHUNK;
    int nrow_bl = (N + 31) / 32;
    int attn_bl = (N + 3) / 4;

    // ---- CSR build ----
    k_zero2<<<(N + 255) / 256, 256, 0, stream>>>(counts, cursor, N);
    k_hist<<<ebl, 256, 0, stream>>>(dstp, E, counts);
    k_scan1<<<nb_scan, SCAN_B, 0, stream>>>(counts, N, offs, bsums);
    k_scan2<<<1, 64, 0, stream>>>(bsums, nb_scan);
    k_scan3<<<(N + 255) / 256, 256, 0, stream>>>(offs, bsums, N, E);
    k_scatter<<<ebl, 256, 0, stream>>>(srcp, dstp, E, offs, cursor, csr);

    // ---- layer 1 (hidden state h1 lives in d_out) ----
    dim3 g1(nrow_bl, 3);
    k_gemm_qkv<<<g1, 256, 0, stream>>>(x, N, Wq1, bq1, Wk1, bk1, Wv1, bv1, Q, K, V);
    k_gemm_s<<<nrow_bl, 256, 0, stream>>>(x, N, Ws1, bs1, S);
    k_attn<<<attn_bl, 256, 0, stream>>>(Q, K, V, S, offs, csr, out, N, 1);

    // ---- layer 2 (reads h1 from d_out, overwrites d_out at the end) ----
    k_gemm_qkv<<<g1, 256, 0, stream>>>(out, N, Wq2, bq2, Wk2, bk2, Wv2, bv2, Q, K, V);
    k_gemm_s<<<nrow_bl, 256, 0, stream>>>(out, N, Ws2, bs2, S);
    k_attn<<<attn_bl, 256, 0, stream>>>(Q, K, V, S, offs, csr, out, N, 0);
}

// Round 4
// 697.525 us; speedup vs baseline: 1.2678x; 1.2678x over previous
//
#include <hip/hip_runtime.h>
#include <hip/hip_fp16.h>
#include <math.h>

// Graph TransformerConv ×2 on MI355X. N=100k, E=800k, D=64, H=4, C=64.
//
// R3: (1) QKV/skip GEMMs moved to bf16 MFMA (16x16x32, K=64 = 2 MFMAs,
//     fp32 accumulate, fp32 bias) — fp32 VALU GEMM was ~2x130 us, MFMA
//     version is memory-bound (~30 us/layer writing 153.6 MB).
//     Weights pre-transposed+cast to bf16 [n][k] so B-frags are contiguous
//     16B loads; X cast to bf16 per layer.
// (2) Attention: K/V interleaved per node (one dwordx4 per lane per edge),
//     v_dot2_f32_f16 for dot products, 2-edge unroll with fused
//     max/rescale to overlap the dependent load->shfl->exp chains.
// Workspace ~197 MB (guarded).

typedef __attribute__((ext_vector_type(8))) short bf16x8;
typedef __attribute__((ext_vector_type(4))) float f32x4;

__device__ inline unsigned short f2bf(float f) {
    unsigned int u = __float_as_uint(f);
    u = (u + 0x7fffu + ((u >> 16) & 1u)) >> 16;
    return (unsigned short)u;
}

__device__ inline float2 h2f(unsigned int u) {
    __half2 h = *(__half2*)&u;
    return __half22float2(h);
}

typedef _Float16 f16x2_t __attribute__((ext_vector_type(2)));
__device__ inline float hdot2(unsigned int a, unsigned int b, float c) {
#if __has_builtin(__builtin_amdgcn_fdot2)
    union { unsigned int u; f16x2_t h; } ua, ub;
    ua.u = a; ub.u = b;
    return __builtin_amdgcn_fdot2(ua.h, ub.h, c, false);
#else
    float2 fa = h2f(a), fb = h2f(b);
    return c + fa.x * fb.x + fa.y * fb.y;
#endif
}

// ---------------- zeroing ----------------
__global__ void k_zero2(int* __restrict__ a, int* __restrict__ b, int n) {
    int i = blockIdx.x * 256 + threadIdx.x;
    if (i < n) { a[i] = 0; b[i] = 0; }
}

// ---------------- CSR build ----------------
__global__ void k_hist(const int* __restrict__ dst, int E, int* __restrict__ counts) {
    int e = blockIdx.x * 256 + threadIdx.x;
    if (e < E) atomicAdd(&counts[dst[e]], 1);
}

#define SCAN_B 256
#define SCAN_CHUNK 2048
__global__ void k_scan1(const int* __restrict__ counts, int n,
                        int* __restrict__ offs, int* __restrict__ bsums) {
    __shared__ int lds[SCAN_B];
    int b = blockIdx.x, tid = threadIdx.x;
    int base = b * SCAN_CHUNK + tid * 8;
    int v[8]; int s = 0;
#pragma unroll
    for (int i = 0; i < 8; ++i) { int idx = base + i; int c = (idx < n) ? counts[idx] : 0; v[i] = s; s += c; }
    lds[tid] = s;
    for (int off = 1; off < SCAN_B; off <<= 1) {
        __syncthreads();
        int x = (tid >= off) ? lds[tid - off] : 0;
        __syncthreads();
        lds[tid] += x;
    }
    __syncthreads();
    int texcl = lds[tid] - s;
#pragma unroll
    for (int i = 0; i < 8; ++i) { int idx = base + i; if (idx < n) offs[idx] = texcl + v[i]; }
    if (tid == SCAN_B - 1) bsums[b] = lds[tid];
}

__global__ void k_scan2(int* bsums, int nb) {
    if (threadIdx.x == 0 && blockIdx.x == 0) {
        int s = 0;
        for (int i = 0; i < nb; ++i) { int c = bsums[i]; bsums[i] = s; s += c; }
    }
}

__global__ void k_scan3(int* __restrict__ offs, const int* __restrict__ bsums, int n, int total) {
    int idx = blockIdx.x * 256 + threadIdx.x;
    if (idx < n) offs[idx] += bsums[idx / SCAN_CHUNK];
    if (idx == 0) offs[n] = total;
}

__global__ void k_scatter(const int* __restrict__ src, const int* __restrict__ dst, int E,
                          const int* __restrict__ offs, int* __restrict__ cursor,
                          int* __restrict__ csr_src) {
    int e = blockIdx.x * 256 + threadIdx.x;
    if (e < E) {
        int d = dst[e];
        int p = offs[d] + atomicAdd(&cursor[d], 1);
        csr_src[p] = src[e];
    }
}

// ---------------- weight prep: transpose + cast to bf16 [n][k] -------------
__global__ void k_prep_w(const float* __restrict__ Wq, const float* __restrict__ Wk,
                         const float* __restrict__ Wv, const float* __restrict__ Ws,
                         unsigned short* __restrict__ Wtq, unsigned short* __restrict__ Wtk,
                         unsigned short* __restrict__ Wtv, unsigned short* __restrict__ Wts) {
    int i = blockIdx.x * 256 + threadIdx.x;
    if (i < 49152) {
        int m = i / 16384, j = i % 16384;
        int n = j / 64, k = j % 64;
        const float* W = (m == 0) ? Wq : (m == 1) ? Wk : Wv;
        unsigned short* Wt = (m == 0) ? Wtq : (m == 1) ? Wtk : Wtv;
        Wt[n * 64 + k] = f2bf(W[k * 256 + n]);
    } else if (i < 53248) {
        int j = i - 49152;
        int n = j / 64, k = j % 64;
        Wts[n * 64 + k] = f2bf(Ws[k * 64 + n]);
    }
}

// ---------------- X cast: fp32 [N,64] -> bf16 ----------------
__global__ void k_cast_x(const float* __restrict__ X, unsigned short* __restrict__ Xb, int n) {
    int i = blockIdx.x * 256 + threadIdx.x;
    if (i * 4 < n) {
        float4 v = ((const float4*)X)[i];
        ushort4 o;
        o.x = f2bf(v.x); o.y = f2bf(v.y); o.z = f2bf(v.z); o.w = f2bf(v.w);
        ((ushort4*)Xb)[i] = o;
    }
}

// ---------------- MFMA GEMM: Xb[N,64] @ Wt^T [64,256] + b ------------------
// blockIdx.y: 0=Q (plain [N,256] fp16), 1=K, 2=V (interleaved into KV rows:
// KV[node] = 512 halves: lane-chunk l = {k[4l..4l+3], v[4l..4l+3]}).
__global__ __launch_bounds__(256) void k_mfma_qkv(
    const unsigned short* __restrict__ Xb, int nrows,
    const unsigned short* __restrict__ Wtq, const float* __restrict__ bq,
    const unsigned short* __restrict__ Wtk, const float* __restrict__ bk,
    const unsigned short* __restrict__ Wtv, const float* __restrict__ bv,
    __half* __restrict__ Q, __half* __restrict__ KV)
{
    int mat = blockIdx.y;
    const unsigned short* Wt = (mat == 0) ? Wtq : (mat == 1) ? Wtk : Wtv;
    const float* bias = (mat == 0) ? bq : (mat == 1) ? bk : bv;
    int wave = threadIdx.x >> 6, lane = threadIdx.x & 63;
    int quad = lane >> 4, n16 = lane & 15;
    int r0 = blockIdx.x * 64 + wave * 16;
    int arow = r0 + n16;
    int arowc = (arow < nrows) ? arow : (nrows - 1);
    bf16x8 a0 = *(const bf16x8*)(Xb + (size_t)arowc * 64 + quad * 8);
    bf16x8 a1 = *(const bf16x8*)(Xb + (size_t)arowc * 64 + 32 + quad * 8);
#pragma unroll 4
    for (int ct = 0; ct < 16; ++ct) {
        const unsigned short* wrow = Wt + (ct * 16 + n16) * 64;
        bf16x8 b0 = *(const bf16x8*)(wrow + quad * 8);
        bf16x8 b1 = *(const bf16x8*)(wrow + 32 + quad * 8);
        f32x4 acc = {0.f, 0.f, 0.f, 0.f};
        acc = __builtin_amdgcn_mfma_f32_16x16x32_bf16(a0, b0, acc, 0, 0, 0);
        acc = __builtin_amdgcn_mfma_f32_16x16x32_bf16(a1, b1, acc, 0, 0, 0);
        int col = ct * 16 + n16;
        float bcol = bias[col];
#pragma unroll
        for (int reg = 0; reg < 4; ++reg) {
            int orow = r0 + quad * 4 + reg;
            if (orow < nrows) {
                __half h = __float2half_rn(acc[reg] + bcol);
                if (mat == 0) {
                    Q[(size_t)orow * 256 + col] = h;
                } else {
                    size_t idx = (size_t)orow * 512 + (size_t)((col >> 2) * 8 + ((mat == 2) ? 4 : 0) + (col & 3));
                    KV[idx] = h;
                }
            }
        }
    }
}

// ---------------- MFMA GEMM: skip path Xb[N,64] @ Wts^T [64,64] + b --------
__global__ __launch_bounds__(256) void k_mfma_s(
    const unsigned short* __restrict__ Xb, int nrows,
    const unsigned short* __restrict__ Wts, const float* __restrict__ bs,
    float* __restrict__ S)
{
    int wave = threadIdx.x >> 6, lane = threadIdx.x & 63;
    int quad = lane >> 4, n16 = lane & 15;
    int r0 = blockIdx.x * 64 + wave * 16;
    int arow = r0 + n16;
    int arowc = (arow < nrows) ? arow : (nrows - 1);
    bf16x8 a0 = *(const bf16x8*)(Xb + (size_t)arowc * 64 + quad * 8);
    bf16x8 a1 = *(const bf16x8*)(Xb + (size_t)arowc * 64 + 32 + quad * 8);
#pragma unroll
    for (int ct = 0; ct < 4; ++ct) {
        const unsigned short* wrow = Wts + (ct * 16 + n16) * 64;
        bf16x8 b0 = *(const bf16x8*)(wrow + quad * 8);
        bf16x8 b1 = *(const bf16x8*)(wrow + 32 + quad * 8);
        f32x4 acc = {0.f, 0.f, 0.f, 0.f};
        acc = __builtin_amdgcn_mfma_f32_16x16x32_bf16(a0, b0, acc, 0, 0, 0);
        acc = __builtin_amdgcn_mfma_f32_16x16x32_bf16(a1, b1, acc, 0, 0, 0);
        int col = ct * 16 + n16;
        float bcol = bs[col];
#pragma unroll
        for (int reg = 0; reg < 4; ++reg) {
            int orow = r0 + quad * 4 + reg;
            if (orow < nrows) S[(size_t)orow * 64 + col] = acc[reg] + bcol;
        }
    }
}

// ---------------- Attention: one wave per destination node ----------------
__global__ __launch_bounds__(256) void k_attn(
    const __half* __restrict__ Q, const __half* __restrict__ KV,
    const float* __restrict__ S,
    const int* __restrict__ offs, const int* __restrict__ csr_src,
    float* __restrict__ out, int n, int relu)
{
    int node = blockIdx.x * 4 + (threadIdx.x >> 6);
    if (node >= n) return;
    int lane = threadIdx.x & 63;
    int li = lane & 15;
    uint2 q = *(const uint2*)(Q + (size_t)node * 256 + lane * 4);
    int beg = offs[node], end = offs[node + 1];
    float m = -3.4e38f, l = 0.f;
    float4 acc = make_float4(0.f, 0.f, 0.f, 0.f);
    int i = beg;
    for (; i + 1 < end; i += 2) {
        int s0 = csr_src[i], s1 = csr_src[i + 1];
        uint4 kv0 = *(const uint4*)(KV + (size_t)s0 * 512 + lane * 8);
        uint4 kv1 = *(const uint4*)(KV + (size_t)s1 * 512 + lane * 8);
        float d0 = hdot2(q.x, kv0.x, hdot2(q.y, kv0.y, 0.f));
        float d1 = hdot2(q.x, kv1.x, hdot2(q.y, kv1.y, 0.f));
        d0 += __shfl_xor(d0, 1); d1 += __shfl_xor(d1, 1);
        d0 += __shfl_xor(d0, 2); d1 += __shfl_xor(d1, 2);
        d0 += __shfl_xor(d0, 4); d1 += __shfl_xor(d1, 4);
        d0 += __shfl_xor(d0, 8); d1 += __shfl_xor(d1, 8);
        float a0 = d0 * 0.125f, a1 = d1 * 0.125f;
        float nm = fmaxf(m, fmaxf(a0, a1));
        float sc = __expf(m - nm);
        float w0 = __expf(a0 - nm);
        float w1 = __expf(a1 - nm);
        m = nm;
        l = l * sc + w0 + w1;
        float2 v0a = h2f(kv0.z), v0b = h2f(kv0.w);
        float2 v1a = h2f(kv1.z), v1b = h2f(kv1.w);
        acc.x = acc.x * sc + v0a.x * w0 + v1a.x * w1;
        acc.y = acc.y * sc + v0a.y * w0 + v1a.y * w1;
        acc.z = acc.z * sc + v0b.x * w0 + v1b.x * w1;
        acc.w = acc.w * sc + v0b.y * w0 + v1b.y * w1;
    }
    if (i < end) {
        int s0 = csr_src[i];
        uint4 kv0 = *(const uint4*)(KV + (size_t)s0 * 512 + lane * 8);
        float d0 = hdot2(q.x, kv0.x, hdot2(q.y, kv0.y, 0.f));
        d0 += __shfl_xor(d0, 1); d0 += __shfl_xor(d0, 2);
        d0 += __shfl_xor(d0, 4); d0 += __shfl_xor(d0, 8);
        float a0 = d0 * 0.125f;
        float nm = fmaxf(m, a0);
        float sc = __expf(m - nm);
        float w0 = __expf(a0 - nm);
        m = nm;
        l = l * sc + w0;
        float2 v0a = h2f(kv0.z), v0b = h2f(kv0.w);
        acc.x = acc.x * sc + v0a.x * w0;
        acc.y = acc.y * sc + v0a.y * w0;
        acc.z = acc.z * sc + v0b.x * w0;
        acc.w = acc.w * sc + v0b.y * w0;
    }
    float inv = 1.f / (l + 1e-16f);
    float4 r = make_float4(acc.x * inv, acc.y * inv, acc.z * inv, acc.w * inv);
    r.x += __shfl_xor(r.x, 16); r.x += __shfl_xor(r.x, 32);
    r.y += __shfl_xor(r.y, 16); r.y += __shfl_xor(r.y, 32);
    r.z += __shfl_xor(r.z, 16); r.z += __shfl_xor(r.z, 32);
    r.w += __shfl_xor(r.w, 16); r.w += __shfl_xor(r.w, 32);
    float4 s4 = *(const float4*)(S + (size_t)node * 64 + li * 4);
    r.x = r.x * 0.25f + s4.x; r.y = r.y * 0.25f + s4.y;
    r.z = r.z * 0.25f + s4.z; r.w = r.w * 0.25f + s4.w;
    if (relu) {
        r.x = fmaxf(r.x, 0.f); r.y = fmaxf(r.y, 0.f);
        r.z = fmaxf(r.z, 0.f); r.w = fmaxf(r.w, 0.f);
    }
    if (lane < 16) *(float4*)(out + (size_t)node * 64 + li * 4) = r;
}

extern "C" void kernel_launch(void* const* d_in, const int* in_sizes, int n_in,
                              void* d_out, int out_size, void* d_ws, size_t ws_size,
                              hipStream_t stream)
{
    const float* x  = (const float*)d_in[0];
    const int*   ei = (const int*)d_in[1];
    int N = in_sizes[0] / 64;
    int E = in_sizes[1] / 2;
    const int* srcp = ei;
    const int* dstp = ei + E;
    const float* Wq1 = (const float*)d_in[2],  *bq1 = (const float*)d_in[3];
    const float* Wk1 = (const float*)d_in[4],  *bk1 = (const float*)d_in[5];
    const float* Wv1 = (const float*)d_in[6],  *bv1 = (const float*)d_in[7];
    const float* Ws1 = (const float*)d_in[8],  *bs1 = (const float*)d_in[9];
    const float* Wq2 = (const float*)d_in[10], *bq2 = (const float*)d_in[11];
    const float* Wk2 = (const float*)d_in[12], *bk2 = (const float*)d_in[13];
    const float* Wv2 = (const float*)d_in[14], *bv2 = (const float*)d_in[15];
    const float* Ws2 = (const float*)d_in[16], *bs2 = (const float*)d_in[17];
    float* out = (float*)d_out;

    // workspace layout (~197 MB)
    char* ws = (char*)d_ws;
    size_t off = 0;
    auto alloc = [&](size_t bytes) -> void* {
        void* p = ws + off;
        off = (off + bytes + 255) & ~(size_t)255;
        return p;
    };
    unsigned short* Xb  = (unsigned short*)alloc((size_t)N * 64 * 2);
    __half* Q           = (__half*)alloc((size_t)N * 256 * 2);
    __half* KV          = (__half*)alloc((size_t)N * 512 * 2);
    float* S            = (float*)alloc((size_t)N * 64 * 4);
    unsigned short* Wtq = (unsigned short*)alloc(256 * 64 * 2);
    unsigned short* Wtk = (unsigned short*)alloc(256 * 64 * 2);
    unsigned short* Wtv = (unsigned short*)alloc(256 * 64 * 2);
    unsigned short* Wts = (unsigned short*)alloc(64 * 64 * 2);
    int* counts = (int*)alloc((size_t)N * 4);
    int* cursor = (int*)alloc((size_t)N * 4);
    int* offs   = (int*)alloc((size_t)(N + 1) * 4);
    int* bsums  = (int*)alloc(1024 * 4);
    int* csr    = (int*)alloc((size_t)E * 4);
    (void)n_in; (void)out_size;
    if (off > ws_size) return;  // diagnostic: too-small ws -> zeros, not a fault

    int ebl = (E + 255) / 256;
    int nb_scan = (N + SCAN_CHUNK - 1) / SCAN_CHUNK;
    int row_bl = (N + 63) / 64;
    int attn_bl = (N + 3) / 4;
    int cast_bl = (N * 64 / 4 + 255) / 256;

    // ---- CSR build ----
    k_zero2<<<(N + 255) / 256, 256, 0, stream>>>(counts, cursor, N);
    k_hist<<<ebl, 256, 0, stream>>>(dstp, E, counts);
    k_scan1<<<nb_scan, SCAN_B, 0, stream>>>(counts, N, offs, bsums);
    k_scan2<<<1, 64, 0, stream>>>(bsums, nb_scan);
    k_scan3<<<(N + 255) / 256, 256, 0, stream>>>(offs, bsums, N, E);
    k_scatter<<<ebl, 256, 0, stream>>>(srcp, dstp, E, offs, cursor, csr);

    // ---- layer 1 ----
    k_prep_w<<<208, 256, 0, stream>>>(Wq1, Wk1, Wv1, Ws1, Wtq, Wtk, Wtv, Wts);
    k_cast_x<<<cast_bl, 256, 0, stream>>>(x, Xb, N * 64);
    dim3 g1(row_bl, 3);
    k_mfma_qkv<<<g1, 256, 0, stream>>>(Xb, N, Wtq, bq1, Wtk, bk1, Wtv, bv1, Q, KV);
    k_mfma_s<<<row_bl, 256, 0, stream>>>(Xb, N, Wts, bs1, S);
    k_attn<<<attn_bl, 256, 0, stream>>>(Q, KV, S, offs, csr, out, N, 1);

    // ---- layer 2 (h1 lives in d_out; cast consumes it before attn overwrites) ----
    k_prep_w<<<208, 256, 0, stream>>>(Wq2, Wk2, Wv2, Ws2, Wtq, Wtk, Wtv, Wts);
    k_cast_x<<<cast_bl, 256, 0, stream>>>(out, Xb, N * 64);
    k_mfma_qkv<<<g1, 256, 0, stream>>>(Xb, N, Wtq, bq2, Wtk, bk2, Wtv, bv2, Q, KV);
    k_mfma_s<<<row_bl, 256, 0, stream>>>(Xb, N, Wts, bs2, S);
    k_attn<<<attn_bl, 256, 0, stream>>>(Q, KV, S, offs, csr, out, N, 0);
}

// Round 5
// 659.416 us; speedup vs baseline: 1.3411x; 1.0578x over previous
//
#include <hip/hip_runtime.h>
#include <hip/hip_fp16.h>
#include <math.h>

// Graph TransformerConv ×2 on MI355X. N=100k, E=800k, D=64, H=4, C=64.
//
// R5: (1) attn restructured to 8-edge batched gathers (broadcast csr indices
//     via shfl, 8 outstanding dwordx4 loads, single softmax-merge per chunk)
//     — attacks the exposed gather latency that capped R4 at 125 us.
// (2) dispatch count 17 -> 10: k_setup fuses X-cast + both layers' weight
//     prep + CSR zeroing; QKV and skip GEMMs fused into one grid (y=4);
//     layer-1 attn writes bf16 Xb directly (no fp32 h1 round-trip, no cast).
// Workspace ~183 MB (guarded).

typedef __attribute__((ext_vector_type(8))) short bf16x8;
typedef __attribute__((ext_vector_type(4))) float f32x4;

__device__ inline unsigned short f2bf(float f) {
    unsigned int u = __float_as_uint(f);
    u = (u + 0x7fffu + ((u >> 16) & 1u)) >> 16;
    return (unsigned short)u;
}

__device__ inline float2 h2f(unsigned int u) {
    __half2 h = *(__half2*)&u;
    return __half22float2(h);
}

typedef _Float16 f16x2_t __attribute__((ext_vector_type(2)));
__device__ inline float hdot2(unsigned int a, unsigned int b, float c) {
#if __has_builtin(__builtin_amdgcn_fdot2)
    union { unsigned int u; f16x2_t h; } ua, ub;
    ua.u = a; ub.u = b;
    return __builtin_amdgcn_fdot2(ua.h, ub.h, c, false);
#else
    float2 fa = h2f(a), fb = h2f(b);
    return c + fa.x * fb.x + fa.y * fb.y;
#endif
}

// ---------------- setup: X cast + weight prep (both layers) + CSR zero -----
// blocks [0, castBl): x fp32 -> Xb bf16 (float4->ushort4)
// blocks [castBl, castBl+416): transpose+cast 8 weight mats into Wt
//   Wt layout per layer (53248 shorts): Wtq[256*64] Wtk Wtv Wts[64*64]
// blocks [castBl+416, ...): zero counts+cursor
__global__ void k_setup(
    const float* __restrict__ x, unsigned short* __restrict__ Xb, int ncast4,
    const float* __restrict__ Wq1, const float* __restrict__ Wk1,
    const float* __restrict__ Wv1, const float* __restrict__ Ws1,
    const float* __restrict__ Wq2, const float* __restrict__ Wk2,
    const float* __restrict__ Wv2, const float* __restrict__ Ws2,
    unsigned short* __restrict__ Wt,
    int* __restrict__ counts, int* __restrict__ cursor, int N, int castBl)
{
    int b = blockIdx.x, tid = threadIdx.x;
    if (b < castBl) {
        int i = b * 256 + tid;
        if (i < ncast4) {
            float4 v = ((const float4*)x)[i];
            ushort4 o;
            o.x = f2bf(v.x); o.y = f2bf(v.y); o.z = f2bf(v.z); o.w = f2bf(v.w);
            ((ushort4*)Xb)[i] = o;
        }
    } else if (b < castBl + 416) {
        int j = (b - castBl) * 256 + tid;   // < 106496
        int layer = j / 53248;
        int r = j % 53248;
        if (r < 49152) {
            int m = r / 16384, w = r % 16384;
            int n = w / 64, k = w % 64;
            const float* W = (layer == 0)
                ? ((m == 0) ? Wq1 : (m == 1) ? Wk1 : Wv1)
                : ((m == 0) ? Wq2 : (m == 1) ? Wk2 : Wv2);
            Wt[layer * 53248 + m * 16384 + n * 64 + k] = f2bf(W[k * 256 + n]);
        } else {
            int w = r - 49152;
            int n = w / 64, k = w % 64;
            const float* W = (layer == 0) ? Ws1 : Ws2;
            Wt[layer * 53248 + 49152 + n * 64 + k] = f2bf(W[k * 64 + n]);
        }
    } else {
        int i = (b - castBl - 416) * 256 + tid;
        if (i < N) { counts[i] = 0; cursor[i] = 0; }
    }
}

// ---------------- CSR build ----------------
__global__ void k_hist(const int* __restrict__ dst, int E, int* __restrict__ counts) {
    int e = blockIdx.x * 256 + threadIdx.x;
    if (e < E) atomicAdd(&counts[dst[e]], 1);
}

#define SCAN_B 256
#define SCAN_CHUNK 2048
__global__ void k_scan1(const int* __restrict__ counts, int n,
                        int* __restrict__ offs, int* __restrict__ bsums) {
    __shared__ int lds[SCAN_B];
    int b = blockIdx.x, tid = threadIdx.x;
    int base = b * SCAN_CHUNK + tid * 8;
    int v[8]; int s = 0;
#pragma unroll
    for (int i = 0; i < 8; ++i) { int idx = base + i; int c = (idx < n) ? counts[idx] : 0; v[i] = s; s += c; }
    lds[tid] = s;
    for (int off = 1; off < SCAN_B; off <<= 1) {
        __syncthreads();
        int x = (tid >= off) ? lds[tid - off] : 0;
        __syncthreads();
        lds[tid] += x;
    }
    __syncthreads();
    int texcl = lds[tid] - s;
#pragma unroll
    for (int i = 0; i < 8; ++i) { int idx = base + i; if (idx < n) offs[idx] = texcl + v[i]; }
    if (tid == SCAN_B - 1) bsums[b] = lds[tid];
}

__global__ void k_scan2(int* bsums, int nb) {
    if (threadIdx.x == 0 && blockIdx.x == 0) {
        int s = 0;
        for (int i = 0; i < nb; ++i) { int c = bsums[i]; bsums[i] = s; s += c; }
    }
}

__global__ void k_scan3(int* __restrict__ offs, const int* __restrict__ bsums, int n, int total) {
    int idx = blockIdx.x * 256 + threadIdx.x;
    if (idx < n) offs[idx] += bsums[idx / SCAN_CHUNK];
    if (idx == 0) offs[n] = total;
}

__global__ void k_scatter(const int* __restrict__ src, const int* __restrict__ dst, int E,
                          const int* __restrict__ offs, int* __restrict__ cursor,
                          int* __restrict__ csr_src) {
    int e = blockIdx.x * 256 + threadIdx.x;
    if (e < E) {
        int d = dst[e];
        int p = offs[d] + atomicAdd(&cursor[d], 1);
        csr_src[p] = src[e];
    }
}

// ---------------- fused MFMA GEMM: Q, K, V, S in one grid (y=0..3) ---------
// y=0: Q [N,256] fp16 plain; y=1/2: K/V interleaved into KV rows
// (KV[node] = 512 halves, lane-chunk l = {k[4l..3], v[4l..3]}); y=3: skip S
// [N,64] fp32 (only 4 col-tiles).
__global__ __launch_bounds__(256) void k_mfma_qkvs(
    const unsigned short* __restrict__ Xb, int nrows,
    const unsigned short* __restrict__ WtL,
    const float* __restrict__ bq, const float* __restrict__ bk,
    const float* __restrict__ bv, const float* __restrict__ bs,
    __half* __restrict__ Q, __half* __restrict__ KV, float* __restrict__ S)
{
    int mat = blockIdx.y;
    const unsigned short* Wt = WtL + ((mat < 3) ? mat * 16384 : 49152);
    const float* bias = (mat == 0) ? bq : (mat == 1) ? bk : (mat == 2) ? bv : bs;
    int nct = (mat == 3) ? 4 : 16;
    int wave = threadIdx.x >> 6, lane = threadIdx.x & 63;
    int quad = lane >> 4, n16 = lane & 15;
    int r0 = blockIdx.x * 64 + wave * 16;
    int arow = r0 + n16;
    int arowc = (arow < nrows) ? arow : (nrows - 1);
    bf16x8 a0 = *(const bf16x8*)(Xb + (size_t)arowc * 64 + quad * 8);
    bf16x8 a1 = *(const bf16x8*)(Xb + (size_t)arowc * 64 + 32 + quad * 8);
    for (int ct = 0; ct < nct; ++ct) {
        const unsigned short* wrow = Wt + (ct * 16 + n16) * 64;
        bf16x8 b0 = *(const bf16x8*)(wrow + quad * 8);
        bf16x8 b1 = *(const bf16x8*)(wrow + 32 + quad * 8);
        f32x4 acc = {0.f, 0.f, 0.f, 0.f};
        acc = __builtin_amdgcn_mfma_f32_16x16x32_bf16(a0, b0, acc, 0, 0, 0);
        acc = __builtin_amdgcn_mfma_f32_16x16x32_bf16(a1, b1, acc, 0, 0, 0);
        int col = ct * 16 + n16;
        float bcol = bias[col];
#pragma unroll
        for (int reg = 0; reg < 4; ++reg) {
            int orow = r0 + quad * 4 + reg;
            if (orow < nrows) {
                float v = acc[reg] + bcol;
                if (mat == 0) {
                    Q[(size_t)orow * 256 + col] = __float2half_rn(v);
                } else if (mat < 3) {
                    size_t idx = (size_t)orow * 512 +
                        (size_t)((col >> 2) * 8 + ((mat == 2) ? 4 : 0) + (col & 3));
                    KV[idx] = __float2half_rn(v);
                } else {
                    S[(size_t)orow * 64 + col] = v;
                }
            }
        }
    }
}

// ---------------- Attention: one wave per dst node, 8-edge batched gathers -
// mode 0: write float4 to out. mode 1: relu, write bf16 to Xb.
__global__ __launch_bounds__(256) void k_attn(
    const __half* __restrict__ Q, const __half* __restrict__ KV,
    const float* __restrict__ S,
    const int* __restrict__ offs, const int* __restrict__ csr_src,
    float* __restrict__ out, unsigned short* __restrict__ Xb, int n, int mode)
{
    int node = blockIdx.x * 4 + (threadIdx.x >> 6);
    if (node >= n) return;
    int lane = threadIdx.x & 63;
    int li = lane & 15;
    uint2 q = *(const uint2*)(Q + (size_t)node * 256 + lane * 4);
    int beg = offs[node], end = offs[node + 1];
    float m = -3.4e38f, l = 0.f;
    float4 acc = make_float4(0.f, 0.f, 0.f, 0.f);
    for (int base = beg; base < end; base += 8) {
        int cnt = end - base; if (cnt > 8) cnt = 8;
        int my = (lane < cnt) ? csr_src[base + lane] : 0;
        int idx[8];
#pragma unroll
        for (int j = 0; j < 8; ++j) idx[j] = __shfl(my, j);
        uint4 kv[8];
#pragma unroll
        for (int j = 0; j < 8; ++j)
            kv[j] = *(const uint4*)(KV + (size_t)idx[j] * 512 + lane * 8);
        float a[8];
#pragma unroll
        for (int j = 0; j < 8; ++j) {
            float d = hdot2(q.x, kv[j].x, hdot2(q.y, kv[j].y, 0.f));
            d += __shfl_xor(d, 1); d += __shfl_xor(d, 2);
            d += __shfl_xor(d, 4); d += __shfl_xor(d, 8);
            a[j] = (j < cnt) ? d * 0.125f : -3.4e38f;
        }
        float M = a[0];
#pragma unroll
        for (int j = 1; j < 8; ++j) M = fmaxf(M, a[j]);
        float nm = fmaxf(m, M);
        float sc = __expf(m - nm);
        m = nm;
        float w[8]; float ls = 0.f;
#pragma unroll
        for (int j = 0; j < 8; ++j) { w[j] = __expf(a[j] - nm); ls += w[j]; }
        l = l * sc + ls;
        float4 vs = make_float4(0.f, 0.f, 0.f, 0.f);
#pragma unroll
        for (int j = 0; j < 8; ++j) {
            float2 va = h2f(kv[j].z), vb = h2f(kv[j].w);
            vs.x += va.x * w[j]; vs.y += va.y * w[j];
            vs.z += vb.x * w[j]; vs.w += vb.y * w[j];
        }
        acc.x = acc.x * sc + vs.x; acc.y = acc.y * sc + vs.y;
        acc.z = acc.z * sc + vs.z; acc.w = acc.w * sc + vs.w;
    }
    float inv = 1.f / (l + 1e-16f);
    float4 r = make_float4(acc.x * inv, acc.y * inv, acc.z * inv, acc.w * inv);
    r.x += __shfl_xor(r.x, 16); r.x += __shfl_xor(r.x, 32);
    r.y += __shfl_xor(r.y, 16); r.y += __shfl_xor(r.y, 32);
    r.z += __shfl_xor(r.z, 16); r.z += __shfl_xor(r.z, 32);
    r.w += __shfl_xor(r.w, 16); r.w += __shfl_xor(r.w, 32);
    float4 s4 = *(const float4*)(S + (size_t)node * 64 + li * 4);
    r.x = r.x * 0.25f + s4.x; r.y = r.y * 0.25f + s4.y;
    r.z = r.z * 0.25f + s4.z; r.w = r.w * 0.25f + s4.w;
    if (mode == 1) {
        if (lane < 16) {
            ushort4 o;
            o.x = f2bf(fmaxf(r.x, 0.f)); o.y = f2bf(fmaxf(r.y, 0.f));
            o.z = f2bf(fmaxf(r.z, 0.f)); o.w = f2bf(fmaxf(r.w, 0.f));
            ((ushort4*)(Xb + (size_t)node * 64))[li] = o;
        }
    } else {
        if (lane < 16) *(float4*)(out + (size_t)node * 64 + li * 4) = r;
    }
}

extern "C" void kernel_launch(void* const* d_in, const int* in_sizes, int n_in,
                              void* d_out, int out_size, void* d_ws, size_t ws_size,
                              hipStream_t stream)
{
    const float* x  = (const float*)d_in[0];
    const int*   ei = (const int*)d_in[1];
    int N = in_sizes[0] / 64;
    int E = in_sizes[1] / 2;
    const int* srcp = ei;
    const int* dstp = ei + E;
    const float* Wq1 = (const float*)d_in[2],  *bq1 = (const float*)d_in[3];
    const float* Wk1 = (const float*)d_in[4],  *bk1 = (const float*)d_in[5];
    const float* Wv1 = (const float*)d_in[6],  *bv1 = (const float*)d_in[7];
    const float* Ws1 = (const float*)d_in[8],  *bs1 = (const float*)d_in[9];
    const float* Wq2 = (const float*)d_in[10], *bq2 = (const float*)d_in[11];
    const float* Wk2 = (const float*)d_in[12], *bk2 = (const float*)d_in[13];
    const float* Wv2 = (const float*)d_in[14], *bv2 = (const float*)d_in[15];
    const float* Ws2 = (const float*)d_in[16], *bs2 = (const float*)d_in[17];
    float* out = (float*)d_out;

    // workspace layout (~183 MB)
    char* ws = (char*)d_ws;
    size_t off = 0;
    auto alloc = [&](size_t bytes) -> void* {
        void* p = ws + off;
        off = (off + bytes + 255) & ~(size_t)255;
        return p;
    };
    unsigned short* Xb  = (unsigned short*)alloc((size_t)N * 64 * 2);
    __half* Q           = (__half*)alloc((size_t)N * 256 * 2);
    __half* KV          = (__half*)alloc((size_t)N * 512 * 2);
    float* S            = (float*)alloc((size_t)N * 64 * 4);
    unsigned short* Wt  = (unsigned short*)alloc(2 * 53248 * 2);
    int* counts = (int*)alloc((size_t)N * 4);
    int* cursor = (int*)alloc((size_t)N * 4);
    int* offs   = (int*)alloc((size_t)(N + 1) * 4);
    int* bsums  = (int*)alloc(1024 * 4);
    int* csr    = (int*)alloc((size_t)E * 4);
    (void)n_in; (void)out_size;
    if (off > ws_size) return;  // diagnostic: too-small ws -> zeros, not a fault

    int ebl = (E + 255) / 256;
    int nb_scan = (N + SCAN_CHUNK - 1) / SCAN_CHUNK;
    int row_bl = (N + 63) / 64;
    int attn_bl = (N + 3) / 4;
    int ncast4 = N * 16;                       // number of float4/ushort4 items
    int castBl = (ncast4 + 255) / 256;
    int zeroBl = (N + 255) / 256;

    // ---- setup: cast X, prep all weights, zero CSR counters (1 launch) ----
    k_setup<<<castBl + 416 + zeroBl, 256, 0, stream>>>(
        x, Xb, ncast4, Wq1, Wk1, Wv1, Ws1, Wq2, Wk2, Wv2, Ws2, Wt,
        counts, cursor, N, castBl);

    // ---- CSR build ----
    k_hist<<<ebl, 256, 0, stream>>>(dstp, E, counts);
    k_scan1<<<nb_scan, SCAN_B, 0, stream>>>(counts, N, offs, bsums);
    k_scan2<<<1, 64, 0, stream>>>(bsums, nb_scan);
    k_scan3<<<(N + 255) / 256, 256, 0, stream>>>(offs, bsums, N, E);
    k_scatter<<<ebl, 256, 0, stream>>>(srcp, dstp, E, offs, cursor, csr);

    dim3 g4(row_bl, 4);
    // ---- layer 1 (h1 goes straight to Xb as bf16; no fp32 round-trip) ----
    k_mfma_qkvs<<<g4, 256, 0, stream>>>(Xb, N, Wt, bq1, bk1, bv1, bs1, Q, KV, S);
    k_attn<<<attn_bl, 256, 0, stream>>>(Q, KV, S, offs, csr, out, Xb, N, 1);

    // ---- layer 2 ----
    k_mfma_qkvs<<<g4, 256, 0, stream>>>(Xb, N, Wt + 53248, bq2, bk2, bv2, bs2, Q, KV, S);
    k_attn<<<attn_bl, 256, 0, stream>>>(Q, KV, S, offs, csr, out, Xb, N, 0);
}

// Round 6
// 603.107 us; speedup vs baseline: 1.4663x; 1.0934x over previous
//
#include <hip/hip_runtime.h>
#include <hip/hip_fp16.h>
#include <math.h>

// Graph TransformerConv ×2 on MI355X. N=100k, E=800k, D=64, H=4, C=64.
//
// R6: k_attn hit a bytes ceiling (~3.7 TB/s L2-miss path, FETCH invariant
// across R4/R5 structures). Reduce bytes: K stored fp8 e4m3 (HW cvt), V fp16
// -> KV row 768 B, one 12-B chunk per lane per edge. Online-max dropped
// (logits bounded; exp(a)/sum == exp(a-m)/sum). GEMM operands swapped so
// each thread owns 4 consecutive CHANNELS of one node -> vectorized packed
// stores (K: dword fp8x4, Q/V: dwordx2, S: dwordx4). CSR: parallel scan2,
// scan3 folded into consumers. 9 dispatches. Workspace ~171 MB (guarded).

typedef __attribute__((ext_vector_type(8))) short bf16x8;
typedef __attribute__((ext_vector_type(4))) float f32x4;
typedef __attribute__((ext_vector_type(2))) float f32x2;

__device__ inline unsigned short f2bf(float f) {
    unsigned int u = __float_as_uint(f);
    u = (u + 0x7fffu + ((u >> 16) & 1u)) >> 16;
    return (unsigned short)u;
}

__device__ inline float2 h2f(unsigned int u) {
    __half2 h = *(__half2*)&u;
    return __half22float2(h);
}

// ---------------- fp8 e4m3 pack/unpack (HW on gfx950) ----------------
#if __has_builtin(__builtin_amdgcn_cvt_pk_fp8_f32) && __has_builtin(__builtin_amdgcn_cvt_pk_f32_fp8)
#define HW_FP8 1
#endif

#ifndef HW_FP8
__device__ inline unsigned int fp8_enc1(float f) {   // fallback, approx RN
    unsigned int u = __float_as_uint(f);
    unsigned int s = (u >> 24) & 0x80u;
    float a = fabsf(f);
    if (a >= 448.f) return s | 0x7Eu;
    if (a < 0.015625f) return s;               // flush subnormal range (fallback only)
    unsigned int ua = __float_as_uint(a);
    unsigned int r = ua + 0x7FFFFu + ((ua >> 20) & 1u);
    int e = (int)((r >> 23) & 255u) - 120;     // e4m3 biased exp
    unsigned int m = (r >> 20) & 7u;
    if (e < 1) return s;
    if (e > 15) return s | 0x7Eu;
    return s | (unsigned int)((e << 3) | m);
}
__device__ inline float fp8_dec1(unsigned int b) {
    unsigned int e = (b >> 3) & 15u, m = b & 7u;
    float v;
    if (e) v = __uint_as_float(((e + 120u) << 23) | (m << 20));
    else   v = (float)m * 0.001953125f;
    return (b & 0x80u) ? -v : v;
}
#endif

__device__ inline unsigned int fp8x4_pack(float f0, float f1, float f2, float f3) {
#ifdef HW_FP8
    int pk = __builtin_amdgcn_cvt_pk_fp8_f32(f0, f1, 0, false);
    pk = __builtin_amdgcn_cvt_pk_fp8_f32(f2, f3, pk, true);
    return (unsigned int)pk;
#else
    return fp8_enc1(f0) | (fp8_enc1(f1) << 8) | (fp8_enc1(f2) << 16) | (fp8_enc1(f3) << 24);
#endif
}

__device__ inline float4 fp8x4_unpack(unsigned int k) {
#ifdef HW_FP8
    f32x2 lo = __builtin_amdgcn_cvt_pk_f32_fp8((int)k, false);
    f32x2 hi = __builtin_amdgcn_cvt_pk_f32_fp8((int)k, true);
    return make_float4(lo[0], lo[1], hi[0], hi[1]);
#else
    return make_float4(fp8_dec1(k & 255u), fp8_dec1((k >> 8) & 255u),
                       fp8_dec1((k >> 16) & 255u), fp8_dec1(k >> 24));
#endif
}

// ---------------- setup: X cast + weight prep (both layers) + CSR zero -----
__global__ void k_setup(
    const float* __restrict__ x, unsigned short* __restrict__ Xb, int ncast4,
    const float* __restrict__ Wq1, const float* __restrict__ Wk1,
    const float* __restrict__ Wv1, const float* __restrict__ Ws1,
    const float* __restrict__ Wq2, const float* __restrict__ Wk2,
    const float* __restrict__ Wv2, const float* __restrict__ Ws2,
    unsigned short* __restrict__ Wt,
    int* __restrict__ counts, int* __restrict__ cursor, int N, int castBl)
{
    int b = blockIdx.x, tid = threadIdx.x;
    if (b < castBl) {
        int i = b * 256 + tid;
        if (i < ncast4) {
            float4 v = ((const float4*)x)[i];
            ushort4 o;
            o.x = f2bf(v.x); o.y = f2bf(v.y); o.z = f2bf(v.z); o.w = f2bf(v.w);
            ((ushort4*)Xb)[i] = o;
        }
    } else if (b < castBl + 416) {
        int j = (b - castBl) * 256 + tid;   // < 106496
        int layer = j / 53248;
        int r = j % 53248;
        if (r < 49152) {
            int m = r / 16384, w = r % 16384;
            int n = w / 64, k = w % 64;
            const float* W = (layer == 0)
                ? ((m == 0) ? Wq1 : (m == 1) ? Wk1 : Wv1)
                : ((m == 0) ? Wq2 : (m == 1) ? Wk2 : Wv2);
            Wt[layer * 53248 + m * 16384 + n * 64 + k] = f2bf(W[k * 256 + n]);
        } else {
            int w = r - 49152;
            int n = w / 64, k = w % 64;
            const float* W = (layer == 0) ? Ws1 : Ws2;
            Wt[layer * 53248 + 49152 + n * 64 + k] = f2bf(W[k * 64 + n]);
        }
    } else {
        int i = (b - castBl - 416) * 256 + tid;
        if (i < N) { counts[i] = 0; cursor[i] = 0; }
    }
}

// ---------------- CSR build ----------------
__global__ void k_hist(const int* __restrict__ dst, int E, int* __restrict__ counts) {
    int e = blockIdx.x * 256 + threadIdx.x;
    if (e < E) atomicAdd(&counts[dst[e]], 1);
}

#define SCAN_B 256
#define SCAN_CHUNK 2048
__global__ void k_scan1(const int* __restrict__ counts, int n,
                        int* __restrict__ offs, int* __restrict__ bsums) {
    __shared__ int lds[SCAN_B];
    int b = blockIdx.x, tid = threadIdx.x;
    int base = b * SCAN_CHUNK + tid * 8;
    int v[8]; int s = 0;
#pragma unroll
    for (int i = 0; i < 8; ++i) { int idx = base + i; int c = (idx < n) ? counts[idx] : 0; v[i] = s; s += c; }
    lds[tid] = s;
    for (int off = 1; off < SCAN_B; off <<= 1) {
        __syncthreads();
        int x = (tid >= off) ? lds[tid - off] : 0;
        __syncthreads();
        lds[tid] += x;
    }
    __syncthreads();
    int texcl = lds[tid] - s;
#pragma unroll
    for (int i = 0; i < 8; ++i) { int idx = base + i; if (idx < n) offs[idx] = texcl + v[i]; }
    if (tid == SCAN_B - 1) bsums[b] = lds[tid];
}

// parallel exclusive scan of bsums (nb <= 64 typical; serial fallback above 256)
__global__ void k_scan2(int* bsums, int nb) {
    __shared__ int lds[256];
    int t = threadIdx.x;
    if (nb > 256) {
        if (t == 0) { int s = 0; for (int i = 0; i < nb; ++i) { int c = bsums[i]; bsums[i] = s; s += c; } }
        return;
    }
    int v = (t < nb) ? bsums[t] : 0;
    lds[t] = v;
    for (int off = 1; off < 256; off <<= 1) {
        __syncthreads();
        int x = (t >= off) ? lds[t - off] : 0;
        __syncthreads();
        lds[t] += x;
    }
    __syncthreads();
    if (t < nb) bsums[t] = lds[t] - v;   // exclusive
}

__global__ void k_scatter(const int* __restrict__ src, const int* __restrict__ dst, int E,
                          const int* __restrict__ offs, const int* __restrict__ bsums,
                          int* __restrict__ cursor, int* __restrict__ csr_src) {
    int e = blockIdx.x * 256 + threadIdx.x;
    if (e < E) {
        int d = dst[e];
        int p = offs[d] + bsums[d >> 11] + atomicAdd(&cursor[d], 1);
        csr_src[p] = src[e];
    }
}

// ---------------- fused MFMA GEMM, operands swapped: D rows = channels -----
// y=0: Q fp16 [node][256]; y=1: K fp8 -> KV bytes [node*768 + 3*ch];
// y=2: V fp16 -> KV bytes [node*768 + 3*ch + 4]; y=3: S fp32 [node][64].
__global__ __launch_bounds__(256) void k_mfma_qkvs(
    const unsigned short* __restrict__ Xb, int nrows,
    const unsigned short* __restrict__ WtL,
    const float* __restrict__ bq, const float* __restrict__ bk,
    const float* __restrict__ bv, const float* __restrict__ bs,
    unsigned char* __restrict__ Qb, unsigned char* __restrict__ KVB,
    float* __restrict__ S)
{
    int mat = blockIdx.y;
    const unsigned short* Wt = WtL + ((mat < 3) ? mat * 16384 : 49152);
    const float* bias = (mat == 0) ? bq : (mat == 1) ? bk : (mat == 2) ? bv : bs;
    int nct = (mat == 3) ? 4 : 16;
    int wave = threadIdx.x >> 6, lane = threadIdx.x & 63;
    int quad = lane >> 4, n16 = lane & 15;
    int r0 = blockIdx.x * 64 + wave * 16;
    int node = r0 + n16;
    int arowc = (node < nrows) ? node : (nrows - 1);
    bf16x8 a0 = *(const bf16x8*)(Xb + (size_t)arowc * 64 + quad * 8);
    bf16x8 a1 = *(const bf16x8*)(Xb + (size_t)arowc * 64 + 32 + quad * 8);
    bool ok = node < nrows;
    for (int ct = 0; ct < nct; ++ct) {
        const unsigned short* wrow = Wt + (ct * 16 + n16) * 64;
        bf16x8 b0 = *(const bf16x8*)(wrow + quad * 8);
        bf16x8 b1 = *(const bf16x8*)(wrow + 32 + quad * 8);
        f32x4 acc = {0.f, 0.f, 0.f, 0.f};
        // A = W (rows=channels), B = X (cols=nodes) -> D row=channel, col=node
        acc = __builtin_amdgcn_mfma_f32_16x16x32_bf16(b0, a0, acc, 0, 0, 0);
        acc = __builtin_amdgcn_mfma_f32_16x16x32_bf16(b1, a1, acc, 0, 0, 0);
        int ch0 = ct * 16 + quad * 4;
        float4 bb = *(const float4*)(bias + ch0);
        float f0 = acc[0] + bb.x, f1 = acc[1] + bb.y;
        float f2 = acc[2] + bb.z, f3 = acc[3] + bb.w;
        if (ok) {
            if (mat == 0) {
                unsigned int lo = (unsigned int)__half_as_ushort(__float2half_rn(f0))
                                | ((unsigned int)__half_as_ushort(__float2half_rn(f1)) << 16);
                unsigned int hi = (unsigned int)__half_as_ushort(__float2half_rn(f2))
                                | ((unsigned int)__half_as_ushort(__float2half_rn(f3)) << 16);
                *(uint2*)(Qb + (size_t)node * 512 + 2 * ch0) = make_uint2(lo, hi);
            } else if (mat == 1) {
                *(unsigned int*)(KVB + (size_t)node * 768 + 3 * ch0) = fp8x4_pack(f0, f1, f2, f3);
            } else if (mat == 2) {
                unsigned int lo = (unsigned int)__half_as_ushort(__float2half_rn(f0))
                                | ((unsigned int)__half_as_ushort(__float2half_rn(f1)) << 16);
                unsigned int hi = (unsigned int)__half_as_ushort(__float2half_rn(f2))
                                | ((unsigned int)__half_as_ushort(__float2half_rn(f3)) << 16);
                unsigned int* p = (unsigned int*)(KVB + (size_t)node * 768 + 3 * ch0 + 4);
                p[0] = lo; p[1] = hi;
            } else {
                *(float4*)(S + (size_t)node * 64 + ch0) = make_float4(f0, f1, f2, f3);
            }
        }
    }
}

// ---------------- Attention: one wave per dst node, no-max softmax ---------
struct __attribute__((aligned(4))) KVC { unsigned int kk, va, vb; };

__global__ __launch_bounds__(256) void k_attn(
    const unsigned char* __restrict__ Qb, const unsigned char* __restrict__ KVB,
    const float* __restrict__ S,
    const int* __restrict__ offs, const int* __restrict__ bsums,
    const int* __restrict__ csr_src,
    float* __restrict__ out, unsigned short* __restrict__ Xb,
    int n, int Etot, int mode)
{
    int node = blockIdx.x * 4 + (threadIdx.x >> 6);
    if (node >= n) return;
    int lane = threadIdx.x & 63;
    int li = lane & 15;
    uint2 qh = *(const uint2*)(Qb + (size_t)node * 512 + lane * 8);
    float2 qa = h2f(qh.x), qb2 = h2f(qh.y);
    float4 q = make_float4(qa.x * 0.125f, qa.y * 0.125f, qb2.x * 0.125f, qb2.y * 0.125f);
    int beg = offs[node] + bsums[node >> 11];
    int end = (node + 1 < n) ? (offs[node + 1] + bsums[(node + 1) >> 11]) : Etot;
    float l = 0.f;
    float4 acc = make_float4(0.f, 0.f, 0.f, 0.f);
    for (int base = beg; base < end; base += 8) {
        int cnt = end - base; if (cnt > 8) cnt = 8;
        int my = (lane < cnt) ? csr_src[base + lane] : 0;
        KVC c[8];
#pragma unroll
        for (int j = 0; j < 8; ++j) {
            int idx = __shfl(my, j);
            c[j] = *(const KVC*)(KVB + (size_t)idx * 768 + lane * 12);
        }
#pragma unroll
        for (int j = 0; j < 8; ++j) {
            float4 k4 = fp8x4_unpack(c[j].kk);
            float d = q.x * k4.x + q.y * k4.y + q.z * k4.z + q.w * k4.w;
            d += __shfl_xor(d, 1); d += __shfl_xor(d, 2);
            d += __shfl_xor(d, 4); d += __shfl_xor(d, 8);
            float w = (j < cnt) ? __expf(d) : 0.f;
            l += w;
            float2 v0 = h2f(c[j].va), v1 = h2f(c[j].vb);
            acc.x += v0.x * w; acc.y += v0.y * w;
            acc.z += v1.x * w; acc.w += v1.y * w;
        }
    }
    float inv = 1.f / (l + 1e-16f);
    float4 r = make_float4(acc.x * inv, acc.y * inv, acc.z * inv, acc.w * inv);
    r.x += __shfl_xor(r.x, 16); r.x += __shfl_xor(r.x, 32);
    r.y += __shfl_xor(r.y, 16); r.y += __shfl_xor(r.y, 32);
    r.z += __shfl_xor(r.z, 16); r.z += __shfl_xor(r.z, 32);
    r.w += __shfl_xor(r.w, 16); r.w += __shfl_xor(r.w, 32);
    float4 s4 = *(const float4*)(S + (size_t)node * 64 + li * 4);
    r.x = r.x * 0.25f + s4.x; r.y = r.y * 0.25f + s4.y;
    r.z = r.z * 0.25f + s4.z; r.w = r.w * 0.25f + s4.w;
    if (mode == 1) {
        if (lane < 16) {
            ushort4 o;
            o.x = f2bf(fmaxf(r.x, 0.f)); o.y = f2bf(fmaxf(r.y, 0.f));
            o.z = f2bf(fmaxf(r.z, 0.f)); o.w = f2bf(fmaxf(r.w, 0.f));
            ((ushort4*)(Xb + (size_t)node * 64))[li] = o;
        }
    } else {
        if (lane < 16) *(float4*)(out + (size_t)node * 64 + li * 4) = r;
    }
}

extern "C" void kernel_launch(void* const* d_in, const int* in_sizes, int n_in,
                              void* d_out, int out_size, void* d_ws, size_t ws_size,
                              hipStream_t stream)
{
    const float* x  = (const float*)d_in[0];
    const int*   ei = (const int*)d_in[1];
    int N = in_sizes[0] / 64;
    int E = in_sizes[1] / 2;
    const int* srcp = ei;
    const int* dstp = ei + E;
    const float* Wq1 = (const float*)d_in[2],  *bq1 = (const float*)d_in[3];
    const float* Wk1 = (const float*)d_in[4],  *bk1 = (const float*)d_in[5];
    const float* Wv1 = (const float*)d_in[6],  *bv1 = (const float*)d_in[7];
    const float* Ws1 = (const float*)d_in[8],  *bs1 = (const float*)d_in[9];
    const float* Wq2 = (const float*)d_in[10], *bq2 = (const float*)d_in[11];
    const float* Wk2 = (const float*)d_in[12], *bk2 = (const float*)d_in[13];
    const float* Wv2 = (const float*)d_in[14], *bv2 = (const float*)d_in[15];
    const float* Ws2 = (const float*)d_in[16], *bs2 = (const float*)d_in[17];
    float* out = (float*)d_out;

    // workspace layout (~171 MB)
    char* ws = (char*)d_ws;
    size_t off = 0;
    auto alloc = [&](size_t bytes) -> void* {
        void* p = ws + off;
        off = (off + bytes + 255) & ~(size_t)255;
        return p;
    };
    unsigned short* Xb = (unsigned short*)alloc((size_t)N * 64 * 2);
    unsigned char* Qb  = (unsigned char*)alloc((size_t)N * 512);
    unsigned char* KVB = (unsigned char*)alloc((size_t)N * 768);
    float* S           = (float*)alloc((size_t)N * 64 * 4);
    unsigned short* Wt = (unsigned short*)alloc(2 * 53248 * 2);
    int* counts = (int*)alloc((size_t)N * 4);
    int* cursor = (int*)alloc((size_t)N * 4);
    int* offs   = (int*)alloc((size_t)N * 4);
    int* bsums  = (int*)alloc(1024 * 4);
    int* csr    = (int*)alloc((size_t)E * 4);
    (void)n_in; (void)out_size;
    if (off > ws_size) return;  // diagnostic: too-small ws -> zeros, not a fault

    int ebl = (E + 255) / 256;
    int nb_scan = (N + SCAN_CHUNK - 1) / SCAN_CHUNK;
    int row_bl = (N + 63) / 64;
    int attn_bl = (N + 3) / 4;
    int ncast4 = N * 16;
    int castBl = (ncast4 + 255) / 256;
    int zeroBl = (N + 255) / 256;

    k_setup<<<castBl + 416 + zeroBl, 256, 0, stream>>>(
        x, Xb, ncast4, Wq1, Wk1, Wv1, Ws1, Wq2, Wk2, Wv2, Ws2, Wt,
        counts, cursor, N, castBl);

    k_hist<<<ebl, 256, 0, stream>>>(dstp, E, counts);
    k_scan1<<<nb_scan, SCAN_B, 0, stream>>>(counts, N, offs, bsums);
    k_scan2<<<1, 256, 0, stream>>>(bsums, nb_scan);
    k_scatter<<<ebl, 256, 0, stream>>>(srcp, dstp, E, offs, bsums, cursor, csr);

    dim3 g4(row_bl, 4);
    // ---- layer 1 (h1 -> Xb bf16 directly) ----
    k_mfma_qkvs<<<g4, 256, 0, stream>>>(Xb, N, Wt, bq1, bk1, bv1, bs1, Qb, KVB, S);
    k_attn<<<attn_bl, 256, 0, stream>>>(Qb, KVB, S, offs, bsums, csr, out, Xb, N, E, 1);

    // ---- layer 2 ----
    k_mfma_qkvs<<<g4, 256, 0, stream>>>(Xb, N, Wt + 53248, bq2, bk2, bv2, bs2, Qb, KVB, S);
    k_attn<<<attn_bl, 256, 0, stream>>>(Qb, KVB, S, offs, bsums, csr, out, Xb, N, E, 0);
}

// Round 7
// 601.581 us; speedup vs baseline: 1.4700x; 1.0025x over previous
//
#include <hip/hip_runtime.h>
#include <hip/hip_fp16.h>
#include <math.h>

// Graph TransformerConv ×2 on MI355X. N=100k, E=800k, D=64, H=4, C=64.
//
// R7: R6's GEMM had 2.3x HBM write amplification (355 vs 154 MB): per-lane
// 4-8 B stores at 512/768-B strides, and K/V written by different blocks
// (different XCD L2s) into the same 64-B lines -> partial-sector writebacks.
// Fix: ONE block computes Q,K,V,S for 64 nodes, stages each output in LDS
// (rows padded +16 B: bank delta 4 -> only free 2-way conflicts), then
// streams contiguous 32/48/16 KB ranges with dwordx4 lanes. k_attn unchanged
// (fp8 K + fp16 V, 768 B/node gather, no-max softmax). 9 dispatches.

typedef __attribute__((ext_vector_type(8))) short bf16x8;
typedef __attribute__((ext_vector_type(4))) float f32x4;
typedef __attribute__((ext_vector_type(2))) float f32x2;

__device__ inline unsigned short f2bf(float f) {
    unsigned int u = __float_as_uint(f);
    u = (u + 0x7fffu + ((u >> 16) & 1u)) >> 16;
    return (unsigned short)u;
}

__device__ inline float2 h2f(unsigned int u) {
    __half2 h = *(__half2*)&u;
    return __half22float2(h);
}

// ---------------- fp8 e4m3 pack/unpack (HW on gfx950) ----------------
#if __has_builtin(__builtin_amdgcn_cvt_pk_fp8_f32) && __has_builtin(__builtin_amdgcn_cvt_pk_f32_fp8)
#define HW_FP8 1
#endif

#ifndef HW_FP8
__device__ inline unsigned int fp8_enc1(float f) {
    unsigned int u = __float_as_uint(f);
    unsigned int s = (u >> 24) & 0x80u;
    float a = fabsf(f);
    if (a >= 448.f) return s | 0x7Eu;
    if (a < 0.015625f) return s;
    unsigned int ua = __float_as_uint(a);
    unsigned int r = ua + 0x7FFFFu + ((ua >> 20) & 1u);
    int e = (int)((r >> 23) & 255u) - 120;
    unsigned int m = (r >> 20) & 7u;
    if (e < 1) return s;
    if (e > 15) return s | 0x7Eu;
    return s | (unsigned int)((e << 3) | m);
}
__device__ inline float fp8_dec1(unsigned int b) {
    unsigned int e = (b >> 3) & 15u, m = b & 7u;
    float v;
    if (e) v = __uint_as_float(((e + 120u) << 23) | (m << 20));
    else   v = (float)m * 0.001953125f;
    return (b & 0x80u) ? -v : v;
}
#endif

__device__ inline unsigned int fp8x4_pack(float f0, float f1, float f2, float f3) {
#ifdef HW_FP8
    int pk = __builtin_amdgcn_cvt_pk_fp8_f32(f0, f1, 0, false);
    pk = __builtin_amdgcn_cvt_pk_fp8_f32(f2, f3, pk, true);
    return (unsigned int)pk;
#else
    return fp8_enc1(f0) | (fp8_enc1(f1) << 8) | (fp8_enc1(f2) << 16) | (fp8_enc1(f3) << 24);
#endif
}

__device__ inline float4 fp8x4_unpack(unsigned int k) {
#ifdef HW_FP8
    f32x2 lo = __builtin_amdgcn_cvt_pk_f32_fp8((int)k, false);
    f32x2 hi = __builtin_amdgcn_cvt_pk_f32_fp8((int)k, true);
    return make_float4(lo[0], lo[1], hi[0], hi[1]);
#else
    return make_float4(fp8_dec1(k & 255u), fp8_dec1((k >> 8) & 255u),
                       fp8_dec1((k >> 16) & 255u), fp8_dec1(k >> 24));
#endif
}

// ---------------- setup: X cast + weight prep (both layers) + CSR zero -----
__global__ void k_setup(
    const float* __restrict__ x, unsigned short* __restrict__ Xb, int ncast4,
    const float* __restrict__ Wq1, const float* __restrict__ Wk1,
    const float* __restrict__ Wv1, const float* __restrict__ Ws1,
    const float* __restrict__ Wq2, const float* __restrict__ Wk2,
    const float* __restrict__ Wv2, const float* __restrict__ Ws2,
    unsigned short* __restrict__ Wt,
    int* __restrict__ counts, int* __restrict__ cursor, int N, int castBl)
{
    int b = blockIdx.x, tid = threadIdx.x;
    if (b < castBl) {
        int i = b * 256 + tid;
        if (i < ncast4) {
            float4 v = ((const float4*)x)[i];
            ushort4 o;
            o.x = f2bf(v.x); o.y = f2bf(v.y); o.z = f2bf(v.z); o.w = f2bf(v.w);
            ((ushort4*)Xb)[i] = o;
        }
    } else if (b < castBl + 416) {
        int j = (b - castBl) * 256 + tid;   // < 106496
        int layer = j / 53248;
        int r = j % 53248;
        if (r < 49152) {
            int m = r / 16384, w = r % 16384;
            int n = w / 64, k = w % 64;
            const float* W = (layer == 0)
                ? ((m == 0) ? Wq1 : (m == 1) ? Wk1 : Wv1)
                : ((m == 0) ? Wq2 : (m == 1) ? Wk2 : Wv2);
            Wt[layer * 53248 + m * 16384 + n * 64 + k] = f2bf(W[k * 256 + n]);
        } else {
            int w = r - 49152;
            int n = w / 64, k = w % 64;
            const float* W = (layer == 0) ? Ws1 : Ws2;
            Wt[layer * 53248 + 49152 + n * 64 + k] = f2bf(W[k * 64 + n]);
        }
    } else {
        int i = (b - castBl - 416) * 256 + tid;
        if (i < N) { counts[i] = 0; cursor[i] = 0; }
    }
}

// ---------------- CSR build ----------------
__global__ void k_hist(const int* __restrict__ dst, int E, int* __restrict__ counts) {
    int e = blockIdx.x * 256 + threadIdx.x;
    if (e < E) atomicAdd(&counts[dst[e]], 1);
}

#define SCAN_B 256
#define SCAN_CHUNK 2048
__global__ void k_scan1(const int* __restrict__ counts, int n,
                        int* __restrict__ offs, int* __restrict__ bsums) {
    __shared__ int lds[SCAN_B];
    int b = blockIdx.x, tid = threadIdx.x;
    int base = b * SCAN_CHUNK + tid * 8;
    int v[8]; int s = 0;
#pragma unroll
    for (int i = 0; i < 8; ++i) { int idx = base + i; int c = (idx < n) ? counts[idx] : 0; v[i] = s; s += c; }
    lds[tid] = s;
    for (int off = 1; off < SCAN_B; off <<= 1) {
        __syncthreads();
        int x = (tid >= off) ? lds[tid - off] : 0;
        __syncthreads();
        lds[tid] += x;
    }
    __syncthreads();
    int texcl = lds[tid] - s;
#pragma unroll
    for (int i = 0; i < 8; ++i) { int idx = base + i; if (idx < n) offs[idx] = texcl + v[i]; }
    if (tid == SCAN_B - 1) bsums[b] = lds[tid];
}

__global__ void k_scan2(int* bsums, int nb) {
    __shared__ int lds[256];
    int t = threadIdx.x;
    if (nb > 256) {
        if (t == 0) { int s = 0; for (int i = 0; i < nb; ++i) { int c = bsums[i]; bsums[i] = s; s += c; } }
        return;
    }
    int v = (t < nb) ? bsums[t] : 0;
    lds[t] = v;
    for (int off = 1; off < 256; off <<= 1) {
        __syncthreads();
        int x = (t >= off) ? lds[t - off] : 0;
        __syncthreads();
        lds[t] += x;
    }
    __syncthreads();
    if (t < nb) bsums[t] = lds[t] - v;   // exclusive
}

__global__ void k_scatter(const int* __restrict__ src, const int* __restrict__ dst, int E,
                          const int* __restrict__ offs, const int* __restrict__ bsums,
                          int* __restrict__ cursor, int* __restrict__ csr_src) {
    int e = blockIdx.x * 256 + threadIdx.x;
    if (e < E) {
        int d = dst[e];
        int p = offs[d] + bsums[d >> 11] + atomicAdd(&cursor[d], 1);
        csr_src[p] = src[e];
    }
}

// ---------------- fused GEMM: Q,K,V,S for 64 nodes per block, LDS-staged ---
// D layout (operand-swapped mfma): col=node (n16), row=channel (quad*4+reg).
// Output layouts (global): Q [node][256 ch fp16] (512 B/row);
// KV [node][64 chunks of 12 B: K fp8x4 | V fp16x4] (768 B/row);
// S [node][64 ch fp32] (256 B/row). Staged in padded LDS, streamed out
// as contiguous dwordx4.
#define QSTR 528   // 512+16
#define KVSTR 784  // 768+16
#define SSTR 272   // 256+16
__global__ __launch_bounds__(256) void k_gemm_fused(
    const unsigned short* __restrict__ Xb, int nrows,
    const unsigned short* __restrict__ WtL,
    const float* __restrict__ bq, const float* __restrict__ bk,
    const float* __restrict__ bv, const float* __restrict__ bs,
    unsigned char* __restrict__ Qb, unsigned char* __restrict__ KVB,
    float* __restrict__ S)
{
    __shared__ char smem[64 * KVSTR];   // 50176 B, reused per phase
    int tid = threadIdx.x;
    int wave = tid >> 6, lane = tid & 63;
    int quad = lane >> 4, n16 = lane & 15;
    int r0 = blockIdx.x * 64;
    int node_local = wave * 16 + n16;
    int arow = r0 + node_local;
    int arowc = (arow < nrows) ? arow : (nrows - 1);
    bf16x8 a0 = *(const bf16x8*)(Xb + (size_t)arowc * 64 + quad * 8);
    bf16x8 a1 = *(const bf16x8*)(Xb + (size_t)arowc * 64 + 32 + quad * 8);
    int valid = nrows - r0; if (valid > 64) valid = 64;

    // ---------- phase Q (Wt offset 0) ----------
    for (int ct = 0; ct < 16; ++ct) {
        const unsigned short* wrow = WtL + (ct * 16 + n16) * 64;
        bf16x8 b0 = *(const bf16x8*)(wrow + quad * 8);
        bf16x8 b1 = *(const bf16x8*)(wrow + 32 + quad * 8);
        f32x4 acc = {0.f, 0.f, 0.f, 0.f};
        acc = __builtin_amdgcn_mfma_f32_16x16x32_bf16(b0, a0, acc, 0, 0, 0);
        acc = __builtin_amdgcn_mfma_f32_16x16x32_bf16(b1, a1, acc, 0, 0, 0);
        int ch0 = ct * 16 + quad * 4;
        float4 bb = *(const float4*)(bq + ch0);
        unsigned int lo = (unsigned int)__half_as_ushort(__float2half_rn(acc[0] + bb.x))
                        | ((unsigned int)__half_as_ushort(__float2half_rn(acc[1] + bb.y)) << 16);
        unsigned int hi = (unsigned int)__half_as_ushort(__float2half_rn(acc[2] + bb.z))
                        | ((unsigned int)__half_as_ushort(__float2half_rn(acc[3] + bb.w)) << 16);
        unsigned int* p = (unsigned int*)(smem + node_local * QSTR + 2 * ch0);
        p[0] = lo; p[1] = hi;
    }
    __syncthreads();
    {
        int lim = valid * 512;
#pragma unroll
        for (int it = 0; it < 8; ++it) {
            int g = it * 4096 + tid * 16;
            if (g < lim) {
                int row = g >> 9, off = g & 511;
                uint4 v = *(const uint4*)(smem + row * QSTR + off);
                *(uint4*)(Qb + (size_t)blockIdx.x * 32768 + g) = v;
            }
        }
    }
    __syncthreads();

    // ---------- phase K (Wt offset 16384) then V (offset 32768) ----------
    for (int ct = 0; ct < 16; ++ct) {
        const unsigned short* wrow = WtL + 16384 + (ct * 16 + n16) * 64;
        bf16x8 b0 = *(const bf16x8*)(wrow + quad * 8);
        bf16x8 b1 = *(const bf16x8*)(wrow + 32 + quad * 8);
        f32x4 acc = {0.f, 0.f, 0.f, 0.f};
        acc = __builtin_amdgcn_mfma_f32_16x16x32_bf16(b0, a0, acc, 0, 0, 0);
        acc = __builtin_amdgcn_mfma_f32_16x16x32_bf16(b1, a1, acc, 0, 0, 0);
        int cg = ct * 4 + quad;               // channel-group = ch0/4
        float4 bb = *(const float4*)(bk + cg * 4);
        *(unsigned int*)(smem + node_local * KVSTR + cg * 12) =
            fp8x4_pack(acc[0] + bb.x, acc[1] + bb.y, acc[2] + bb.z, acc[3] + bb.w);
    }
    for (int ct = 0; ct < 16; ++ct) {
        const unsigned short* wrow = WtL + 32768 + (ct * 16 + n16) * 64;
        bf16x8 b0 = *(const bf16x8*)(wrow + quad * 8);
        bf16x8 b1 = *(const bf16x8*)(wrow + 32 + quad * 8);
        f32x4 acc = {0.f, 0.f, 0.f, 0.f};
        acc = __builtin_amdgcn_mfma_f32_16x16x32_bf16(b0, a0, acc, 0, 0, 0);
        acc = __builtin_amdgcn_mfma_f32_16x16x32_bf16(b1, a1, acc, 0, 0, 0);
        int cg = ct * 4 + quad;
        float4 bb = *(const float4*)(bv + cg * 4);
        unsigned int lo = (unsigned int)__half_as_ushort(__float2half_rn(acc[0] + bb.x))
                        | ((unsigned int)__half_as_ushort(__float2half_rn(acc[1] + bb.y)) << 16);
        unsigned int hi = (unsigned int)__half_as_ushort(__float2half_rn(acc[2] + bb.z))
                        | ((unsigned int)__half_as_ushort(__float2half_rn(acc[3] + bb.w)) << 16);
        unsigned int* p = (unsigned int*)(smem + node_local * KVSTR + cg * 12 + 4);
        p[0] = lo; p[1] = hi;
    }
    __syncthreads();
    {
        int lim = valid * 768;
#pragma unroll
        for (int it = 0; it < 12; ++it) {
            int g = it * 4096 + tid * 16;
            if (g < lim) {
                int row = g / 768, off = g - row * 768;
                uint4 v = *(const uint4*)(smem + row * KVSTR + off);
                *(uint4*)(KVB + (size_t)blockIdx.x * 49152 + g) = v;
            }
        }
    }
    __syncthreads();

    // ---------- phase S (Wt offset 49152) ----------
    for (int ct = 0; ct < 4; ++ct) {
        const unsigned short* wrow = WtL + 49152 + (ct * 16 + n16) * 64;
        bf16x8 b0 = *(const bf16x8*)(wrow + quad * 8);
        bf16x8 b1 = *(const bf16x8*)(wrow + 32 + quad * 8);
        f32x4 acc = {0.f, 0.f, 0.f, 0.f};
        acc = __builtin_amdgcn_mfma_f32_16x16x32_bf16(b0, a0, acc, 0, 0, 0);
        acc = __builtin_amdgcn_mfma_f32_16x16x32_bf16(b1, a1, acc, 0, 0, 0);
        int ch0 = ct * 16 + quad * 4;
        float4 bb = *(const float4*)(bs + ch0);
        float4 o = make_float4(acc[0] + bb.x, acc[1] + bb.y, acc[2] + bb.z, acc[3] + bb.w);
        *(float4*)(smem + node_local * SSTR + ch0 * 4) = o;
    }
    __syncthreads();
    {
        int lim = valid * 256;
#pragma unroll
        for (int it = 0; it < 4; ++it) {
            int g = it * 4096 + tid * 16;
            if (g < lim) {
                int row = g >> 8, off = g & 255;
                uint4 v = *(const uint4*)(smem + row * SSTR + off);
                *(uint4*)((unsigned char*)S + (size_t)blockIdx.x * 16384 + g) = v;
            }
        }
    }
}

// ---------------- Attention: one wave per dst node, no-max softmax ---------
struct __attribute__((aligned(4))) KVC { unsigned int kk, va, vb; };

__global__ __launch_bounds__(256) void k_attn(
    const unsigned char* __restrict__ Qb, const unsigned char* __restrict__ KVB,
    const float* __restrict__ S,
    const int* __restrict__ offs, const int* __restrict__ bsums,
    const int* __restrict__ csr_src,
    float* __restrict__ out, unsigned short* __restrict__ Xb,
    int n, int Etot, int mode)
{
    int node = blockIdx.x * 4 + (threadIdx.x >> 6);
    if (node >= n) return;
    int lane = threadIdx.x & 63;
    int li = lane & 15;
    uint2 qh = *(const uint2*)(Qb + (size_t)node * 512 + lane * 8);
    float2 qa = h2f(qh.x), qb2 = h2f(qh.y);
    float4 q = make_float4(qa.x * 0.125f, qa.y * 0.125f, qb2.x * 0.125f, qb2.y * 0.125f);
    int beg = offs[node] + bsums[node >> 11];
    int end = (node + 1 < n) ? (offs[node + 1] + bsums[(node + 1) >> 11]) : Etot;
    float l = 0.f;
    float4 acc = make_float4(0.f, 0.f, 0.f, 0.f);
    for (int base = beg; base < end; base += 8) {
        int cnt = end - base; if (cnt > 8) cnt = 8;
        int my = (lane < cnt) ? csr_src[base + lane] : 0;
        KVC c[8];
#pragma unroll
        for (int j = 0; j < 8; ++j) {
            int idx = __shfl(my, j);
            c[j] = *(const KVC*)(KVB + (size_t)idx * 768 + lane * 12);
        }
#pragma unroll
        for (int j = 0; j < 8; ++j) {
            float4 k4 = fp8x4_unpack(c[j].kk);
            float d = q.x * k4.x + q.y * k4.y + q.z * k4.z + q.w * k4.w;
            d += __shfl_xor(d, 1); d += __shfl_xor(d, 2);
            d += __shfl_xor(d, 4); d += __shfl_xor(d, 8);
            float w = (j < cnt) ? __expf(d) : 0.f;
            l += w;
            float2 v0 = h2f(c[j].va), v1 = h2f(c[j].vb);
            acc.x += v0.x * w; acc.y += v0.y * w;
            acc.z += v1.x * w; acc.w += v1.y * w;
        }
    }
    float inv = 1.f / (l + 1e-16f);
    float4 r = make_float4(acc.x * inv, acc.y * inv, acc.z * inv, acc.w * inv);
    r.x += __shfl_xor(r.x, 16); r.x += __shfl_xor(r.x, 32);
    r.y += __shfl_xor(r.y, 16); r.y += __shfl_xor(r.y, 32);
    r.z += __shfl_xor(r.z, 16); r.z += __shfl_xor(r.z, 32);
    r.w += __shfl_xor(r.w, 16); r.w += __shfl_xor(r.w, 32);
    float4 s4 = *(const float4*)(S + (size_t)node * 64 + li * 4);
    r.x = r.x * 0.25f + s4.x; r.y = r.y * 0.25f + s4.y;
    r.z = r.z * 0.25f + s4.z; r.w = r.w * 0.25f + s4.w;
    if (mode == 1) {
        if (lane < 16) {
            ushort4 o;
            o.x = f2bf(fmaxf(r.x, 0.f)); o.y = f2bf(fmaxf(r.y, 0.f));
            o.z = f2bf(fmaxf(r.z, 0.f)); o.w = f2bf(fmaxf(r.w, 0.f));
            ((ushort4*)(Xb + (size_t)node * 64))[li] = o;
        }
    } else {
        if (lane < 16) *(float4*)(out + (size_t)node * 64 + li * 4) = r;
    }
}

extern "C" void kernel_launch(void* const* d_in, const int* in_sizes, int n_in,
                              void* d_out, int out_size, void* d_ws, size_t ws_size,
                              hipStream_t stream)
{
    const float* x  = (const float*)d_in[0];
    const int*   ei = (const int*)d_in[1];
    int N = in_sizes[0] / 64;
    int E = in_sizes[1] / 2;
    const int* srcp = ei;
    const int* dstp = ei + E;
    const float* Wq1 = (const float*)d_in[2],  *bq1 = (const float*)d_in[3];
    const float* Wk1 = (const float*)d_in[4],  *bk1 = (const float*)d_in[5];
    const float* Wv1 = (const float*)d_in[6],  *bv1 = (const float*)d_in[7];
    const float* Ws1 = (const float*)d_in[8],  *bs1 = (const float*)d_in[9];
    const float* Wq2 = (const float*)d_in[10], *bq2 = (const float*)d_in[11];
    const float* Wk2 = (const float*)d_in[12], *bk2 = (const float*)d_in[13];
    const float* Wv2 = (const float*)d_in[14], *bv2 = (const float*)d_in[15];
    const float* Ws2 = (const float*)d_in[16], *bs2 = (const float*)d_in[17];
    float* out = (float*)d_out;

    // workspace layout (~171 MB)
    char* ws = (char*)d_ws;
    size_t off = 0;
    auto alloc = [&](size_t bytes) -> void* {
        void* p = ws + off;
        off = (off + bytes + 255) & ~(size_t)255;
        return p;
    };
    unsigned short* Xb = (unsigned short*)alloc((size_t)N * 64 * 2);
    unsigned char* Qb  = (unsigned char*)alloc(((size_t)N + 64) * 512);
    unsigned char* KVB = (unsigned char*)alloc(((size_t)N + 64) * 768);
    float* S           = (float*)alloc(((size_t)N + 64) * 64 * 4);
    unsigned short* Wt = (unsigned short*)alloc(2 * 53248 * 2);
    int* counts = (int*)alloc((size_t)N * 4);
    int* cursor = (int*)alloc((size_t)N * 4);
    int* offs   = (int*)alloc((size_t)N * 4);
    int* bsums  = (int*)alloc(1024 * 4);
    int* csr    = (int*)alloc((size_t)E * 4);
    (void)n_in; (void)out_size;
    if (off > ws_size) return;  // diagnostic: too-small ws -> zeros, not a fault

    int ebl = (E + 255) / 256;
    int nb_scan = (N + SCAN_CHUNK - 1) / SCAN_CHUNK;
    int row_bl = (N + 63) / 64;
    int attn_bl = (N + 3) / 4;
    int ncast4 = N * 16;
    int castBl = (ncast4 + 255) / 256;
    int zeroBl = (N + 255) / 256;

    k_setup<<<castBl + 416 + zeroBl, 256, 0, stream>>>(
        x, Xb, ncast4, Wq1, Wk1, Wv1, Ws1, Wq2, Wk2, Wv2, Ws2, Wt,
        counts, cursor, N, castBl);

    k_hist<<<ebl, 256, 0, stream>>>(dstp, E, counts);
    k_scan1<<<nb_scan, SCAN_B, 0, stream>>>(counts, N, offs, bsums);
    k_scan2<<<1, 256, 0, stream>>>(bsums, nb_scan);
    k_scatter<<<ebl, 256, 0, stream>>>(srcp, dstp, E, offs, bsums, cursor, csr);

    // ---- layer 1 (h1 -> Xb bf16 directly) ----
    k_gemm_fused<<<row_bl, 256, 0, stream>>>(Xb, N, Wt, bq1, bk1, bv1, bs1, Qb, KVB, S);
    k_attn<<<attn_bl, 256, 0, stream>>>(Qb, KVB, S, offs, bsums, csr, out, Xb, N, E, 1);

    // ---- layer 2 ----
    k_gemm_fused<<<row_bl, 256, 0, stream>>>(Xb, N, Wt + 53248, bq2, bk2, bv2, bs2, Qb, KVB, S);
    k_attn<<<attn_bl, 256, 0, stream>>>(Qb, KVB, S, offs, bsums, csr, out, Xb, N, E, 0);
}

// Round 8
// 589.735 us; speedup vs baseline: 1.4995x; 1.0201x over previous
//
#include <hip/hip_runtime.h>
#include <hip/hip_fp16.h>
#include <math.h>

// Graph TransformerConv ×2 on MI355X. N=100k, E=800k, D=64, H=4, C=64.
//
// R8: R7 showed LDS staging fixes write amplification but kills occupancy
// (26%, serialized barrier phases) -> same 114 us. Revert to R6's no-LDS
// high-occupancy grid (y=0..3), fix amplification by LAYOUT: K and V in
// SEPARATE dense buffers (K fp8 256 B/row, V fp16 512 B/row) so every 64-B
// line is fully written by one wave of one block (no cross-XCD partial
// lines). Attn gathers K (dword) + V (uint2) separately: same bytes/edge.
// 9 dispatches. Workspace ~171 MB (guarded).

typedef __attribute__((ext_vector_type(8))) short bf16x8;
typedef __attribute__((ext_vector_type(4))) float f32x4;
typedef __attribute__((ext_vector_type(2))) float f32x2;

__device__ inline unsigned short f2bf(float f) {
    unsigned int u = __float_as_uint(f);
    u = (u + 0x7fffu + ((u >> 16) & 1u)) >> 16;
    return (unsigned short)u;
}

__device__ inline float2 h2f(unsigned int u) {
    __half2 h = *(__half2*)&u;
    return __half22float2(h);
}

// ---------------- fp8 e4m3 pack/unpack (HW on gfx950) ----------------
#if __has_builtin(__builtin_amdgcn_cvt_pk_fp8_f32) && __has_builtin(__builtin_amdgcn_cvt_pk_f32_fp8)
#define HW_FP8 1
#endif

#ifndef HW_FP8
__device__ inline unsigned int fp8_enc1(float f) {
    unsigned int u = __float_as_uint(f);
    unsigned int s = (u >> 24) & 0x80u;
    float a = fabsf(f);
    if (a >= 448.f) return s | 0x7Eu;
    if (a < 0.015625f) return s;
    unsigned int ua = __float_as_uint(a);
    unsigned int r = ua + 0x7FFFFu + ((ua >> 20) & 1u);
    int e = (int)((r >> 23) & 255u) - 120;
    unsigned int m = (r >> 20) & 7u;
    if (e < 1) return s;
    if (e > 15) return s | 0x7Eu;
    return s | (unsigned int)((e << 3) | m);
}
__device__ inline float fp8_dec1(unsigned int b) {
    unsigned int e = (b >> 3) & 15u, m = b & 7u;
    float v;
    if (e) v = __uint_as_float(((e + 120u) << 23) | (m << 20));
    else   v = (float)m * 0.001953125f;
    return (b & 0x80u) ? -v : v;
}
#endif

__device__ inline unsigned int fp8x4_pack(float f0, float f1, float f2, float f3) {
#ifdef HW_FP8
    int pk = __builtin_amdgcn_cvt_pk_fp8_f32(f0, f1, 0, false);
    pk = __builtin_amdgcn_cvt_pk_fp8_f32(f2, f3, pk, true);
    return (unsigned int)pk;
#else
    return fp8_enc1(f0) | (fp8_enc1(f1) << 8) | (fp8_enc1(f2) << 16) | (fp8_enc1(f3) << 24);
#endif
}

__device__ inline float4 fp8x4_unpack(unsigned int k) {
#ifdef HW_FP8
    f32x2 lo = __builtin_amdgcn_cvt_pk_f32_fp8((int)k, false);
    f32x2 hi = __builtin_amdgcn_cvt_pk_f32_fp8((int)k, true);
    return make_float4(lo[0], lo[1], hi[0], hi[1]);
#else
    return make_float4(fp8_dec1(k & 255u), fp8_dec1((k >> 8) & 255u),
                       fp8_dec1((k >> 16) & 255u), fp8_dec1(k >> 24));
#endif
}

// ---------------- setup: X cast + weight prep (both layers) + CSR zero -----
__global__ void k_setup(
    const float* __restrict__ x, unsigned short* __restrict__ Xb, int ncast4,
    const float* __restrict__ Wq1, const float* __restrict__ Wk1,
    const float* __restrict__ Wv1, const float* __restrict__ Ws1,
    const float* __restrict__ Wq2, const float* __restrict__ Wk2,
    const float* __restrict__ Wv2, const float* __restrict__ Ws2,
    unsigned short* __restrict__ Wt,
    int* __restrict__ counts, int* __restrict__ cursor, int N, int castBl)
{
    int b = blockIdx.x, tid = threadIdx.x;
    if (b < castBl) {
        int i = b * 256 + tid;
        if (i < ncast4) {
            float4 v = ((const float4*)x)[i];
            ushort4 o;
            o.x = f2bf(v.x); o.y = f2bf(v.y); o.z = f2bf(v.z); o.w = f2bf(v.w);
            ((ushort4*)Xb)[i] = o;
        }
    } else if (b < castBl + 416) {
        int j = (b - castBl) * 256 + tid;   // < 106496
        int layer = j / 53248;
        int r = j % 53248;
        if (r < 49152) {
            int m = r / 16384, w = r % 16384;
            int n = w / 64, k = w % 64;
            const float* W = (layer == 0)
                ? ((m == 0) ? Wq1 : (m == 1) ? Wk1 : Wv1)
                : ((m == 0) ? Wq2 : (m == 1) ? Wk2 : Wv2);
            Wt[layer * 53248 + m * 16384 + n * 64 + k] = f2bf(W[k * 256 + n]);
        } else {
            int w = r - 49152;
            int n = w / 64, k = w % 64;
            const float* W = (layer == 0) ? Ws1 : Ws2;
            Wt[layer * 53248 + 49152 + n * 64 + k] = f2bf(W[k * 64 + n]);
        }
    } else {
        int i = (b - castBl - 416) * 256 + tid;
        if (i < N) { counts[i] = 0; cursor[i] = 0; }
    }
}

// ---------------- CSR build ----------------
__global__ void k_hist(const int* __restrict__ dst, int E, int* __restrict__ counts) {
    int e = blockIdx.x * 256 + threadIdx.x;
    if (e < E) atomicAdd(&counts[dst[e]], 1);
}

#define SCAN_B 256
#define SCAN_CHUNK 2048
__global__ void k_scan1(const int* __restrict__ counts, int n,
                        int* __restrict__ offs, int* __restrict__ bsums) {
    __shared__ int lds[SCAN_B];
    int b = blockIdx.x, tid = threadIdx.x;
    int base = b * SCAN_CHUNK + tid * 8;
    int v[8]; int s = 0;
#pragma unroll
    for (int i = 0; i < 8; ++i) { int idx = base + i; int c = (idx < n) ? counts[idx] : 0; v[i] = s; s += c; }
    lds[tid] = s;
    for (int off = 1; off < SCAN_B; off <<= 1) {
        __syncthreads();
        int x = (tid >= off) ? lds[tid - off] : 0;
        __syncthreads();
        lds[tid] += x;
    }
    __syncthreads();
    int texcl = lds[tid] - s;
#pragma unroll
    for (int i = 0; i < 8; ++i) { int idx = base + i; if (idx < n) offs[idx] = texcl + v[i]; }
    if (tid == SCAN_B - 1) bsums[b] = lds[tid];
}

__global__ void k_scan2(int* bsums, int nb) {
    __shared__ int lds[256];
    int t = threadIdx.x;
    if (nb > 256) {
        if (t == 0) { int s = 0; for (int i = 0; i < nb; ++i) { int c = bsums[i]; bsums[i] = s; s += c; } }
        return;
    }
    int v = (t < nb) ? bsums[t] : 0;
    lds[t] = v;
    for (int off = 1; off < 256; off <<= 1) {
        __syncthreads();
        int x = (t >= off) ? lds[t - off] : 0;
        __syncthreads();
        lds[t] += x;
    }
    __syncthreads();
    if (t < nb) bsums[t] = lds[t] - v;   // exclusive
}

__global__ void k_scatter(const int* __restrict__ src, const int* __restrict__ dst, int E,
                          const int* __restrict__ offs, const int* __restrict__ bsums,
                          int* __restrict__ cursor, int* __restrict__ csr_src) {
    int e = blockIdx.x * 256 + threadIdx.x;
    if (e < E) {
        int d = dst[e];
        int p = offs[d] + bsums[d >> 11] + atomicAdd(&cursor[d], 1);
        csr_src[p] = src[e];
    }
}

// ---------------- fused MFMA GEMM, separate dense outputs ------------------
// Operand-swapped mfma: D col=node (n16), row=channel (quad*4+reg).
// y=0: Q fp16 [node][256ch] (512 B/row, uint2 stores)
// y=1: K fp8  [node][256ch] (256 B/row, dword stores)
// y=2: V fp16 [node][256ch] (512 B/row, uint2 stores)
// y=3: S fp32 [node][64ch]  (256 B/row, dwordx4 stores)
// Every 64-B line of every output is written entirely by one wave.
__global__ __launch_bounds__(256) void k_mfma_qkvs(
    const unsigned short* __restrict__ Xb, int nrows,
    const unsigned short* __restrict__ WtL,
    const float* __restrict__ bq, const float* __restrict__ bk,
    const float* __restrict__ bv, const float* __restrict__ bs,
    unsigned char* __restrict__ Qb, unsigned char* __restrict__ Kb,
    unsigned char* __restrict__ Vb, float* __restrict__ S)
{
    int mat = blockIdx.y;
    const unsigned short* Wt = WtL + ((mat < 3) ? mat * 16384 : 49152);
    const float* bias = (mat == 0) ? bq : (mat == 1) ? bk : (mat == 2) ? bv : bs;
    int nct = (mat == 3) ? 4 : 16;
    int wave = threadIdx.x >> 6, lane = threadIdx.x & 63;
    int quad = lane >> 4, n16 = lane & 15;
    int r0 = blockIdx.x * 64 + wave * 16;
    int node = r0 + n16;
    int arowc = (node < nrows) ? node : (nrows - 1);
    bf16x8 a0 = *(const bf16x8*)(Xb + (size_t)arowc * 64 + quad * 8);
    bf16x8 a1 = *(const bf16x8*)(Xb + (size_t)arowc * 64 + 32 + quad * 8);
    bool ok = node < nrows;
    for (int ct = 0; ct < nct; ++ct) {
        const unsigned short* wrow = Wt + (ct * 16 + n16) * 64;
        bf16x8 b0 = *(const bf16x8*)(wrow + quad * 8);
        bf16x8 b1 = *(const bf16x8*)(wrow + 32 + quad * 8);
        f32x4 acc = {0.f, 0.f, 0.f, 0.f};
        acc = __builtin_amdgcn_mfma_f32_16x16x32_bf16(b0, a0, acc, 0, 0, 0);
        acc = __builtin_amdgcn_mfma_f32_16x16x32_bf16(b1, a1, acc, 0, 0, 0);
        int ch0 = ct * 16 + quad * 4;
        float4 bb = *(const float4*)(bias + ch0);
        float f0 = acc[0] + bb.x, f1 = acc[1] + bb.y;
        float f2 = acc[2] + bb.z, f3 = acc[3] + bb.w;
        if (ok) {
            if (mat == 1) {
                *(unsigned int*)(Kb + (size_t)node * 256 + ch0) = fp8x4_pack(f0, f1, f2, f3);
            } else if (mat == 3) {
                *(float4*)(S + (size_t)node * 64 + ch0) = make_float4(f0, f1, f2, f3);
            } else {
                unsigned int lo = (unsigned int)__half_as_ushort(__float2half_rn(f0))
                                | ((unsigned int)__half_as_ushort(__float2half_rn(f1)) << 16);
                unsigned int hi = (unsigned int)__half_as_ushort(__float2half_rn(f2))
                                | ((unsigned int)__half_as_ushort(__float2half_rn(f3)) << 16);
                unsigned char* base = (mat == 0) ? Qb : Vb;
                *(uint2*)(base + (size_t)node * 512 + 2 * ch0) = make_uint2(lo, hi);
            }
        }
    }
}

// ---------------- Attention: one wave per dst node, no-max softmax ---------
__global__ __launch_bounds__(256) void k_attn(
    const unsigned char* __restrict__ Qb, const unsigned char* __restrict__ Kb,
    const unsigned char* __restrict__ Vb, const float* __restrict__ S,
    const int* __restrict__ offs, const int* __restrict__ bsums,
    const int* __restrict__ csr_src,
    float* __restrict__ out, unsigned short* __restrict__ Xb,
    int n, int Etot, int mode)
{
    int node = blockIdx.x * 4 + (threadIdx.x >> 6);
    if (node >= n) return;
    int lane = threadIdx.x & 63;
    int li = lane & 15;
    uint2 qh = *(const uint2*)(Qb + (size_t)node * 512 + lane * 8);
    float2 qa = h2f(qh.x), qb2 = h2f(qh.y);
    float4 q = make_float4(qa.x * 0.125f, qa.y * 0.125f, qb2.x * 0.125f, qb2.y * 0.125f);
    int beg = offs[node] + bsums[node >> 11];
    int end = (node + 1 < n) ? (offs[node + 1] + bsums[(node + 1) >> 11]) : Etot;
    float l = 0.f;
    float4 acc = make_float4(0.f, 0.f, 0.f, 0.f);
    for (int base = beg; base < end; base += 8) {
        int cnt = end - base; if (cnt > 8) cnt = 8;
        int my = (lane < cnt) ? csr_src[base + lane] : 0;
        unsigned int kk[8]; uint2 vv[8];
#pragma unroll
        for (int j = 0; j < 8; ++j) {
            int idx = __shfl(my, j);
            kk[j] = *(const unsigned int*)(Kb + (size_t)idx * 256 + lane * 4);
            vv[j] = *(const uint2*)(Vb + (size_t)idx * 512 + lane * 8);
        }
#pragma unroll
        for (int j = 0; j < 8; ++j) {
            float4 k4 = fp8x4_unpack(kk[j]);
            float d = q.x * k4.x + q.y * k4.y + q.z * k4.z + q.w * k4.w;
            d += __shfl_xor(d, 1); d += __shfl_xor(d, 2);
            d += __shfl_xor(d, 4); d += __shfl_xor(d, 8);
            float w = (j < cnt) ? __expf(d) : 0.f;
            l += w;
            float2 v0 = h2f(vv[j].x), v1 = h2f(vv[j].y);
            acc.x += v0.x * w; acc.y += v0.y * w;
            acc.z += v1.x * w; acc.w += v1.y * w;
        }
    }
    float inv = 1.f / (l + 1e-16f);
    float4 r = make_float4(acc.x * inv, acc.y * inv, acc.z * inv, acc.w * inv);
    r.x += __shfl_xor(r.x, 16); r.x += __shfl_xor(r.x, 32);
    r.y += __shfl_xor(r.y, 16); r.y += __shfl_xor(r.y, 32);
    r.z += __shfl_xor(r.z, 16); r.z += __shfl_xor(r.z, 32);
    r.w += __shfl_xor(r.w, 16); r.w += __shfl_xor(r.w, 32);
    float4 s4 = *(const float4*)(S + (size_t)node * 64 + li * 4);
    r.x = r.x * 0.25f + s4.x; r.y = r.y * 0.25f + s4.y;
    r.z = r.z * 0.25f + s4.z; r.w = r.w * 0.25f + s4.w;
    if (mode == 1) {
        if (lane < 16) {
            ushort4 o;
            o.x = f2bf(fmaxf(r.x, 0.f)); o.y = f2bf(fmaxf(r.y, 0.f));
            o.z = f2bf(fmaxf(r.z, 0.f)); o.w = f2bf(fmaxf(r.w, 0.f));
            ((ushort4*)(Xb + (size_t)node * 64))[li] = o;
        }
    } else {
        if (lane < 16) *(float4*)(out + (size_t)node * 64 + li * 4) = r;
    }
}

extern "C" void kernel_launch(void* const* d_in, const int* in_sizes, int n_in,
                              void* d_out, int out_size, void* d_ws, size_t ws_size,
                              hipStream_t stream)
{
    const float* x  = (const float*)d_in[0];
    const int*   ei = (const int*)d_in[1];
    int N = in_sizes[0] / 64;
    int E = in_sizes[1] / 2;
    const int* srcp = ei;
    const int* dstp = ei + E;
    const float* Wq1 = (const float*)d_in[2],  *bq1 = (const float*)d_in[3];
    const float* Wk1 = (const float*)d_in[4],  *bk1 = (const float*)d_in[5];
    const float* Wv1 = (const float*)d_in[6],  *bv1 = (const float*)d_in[7];
    const float* Ws1 = (const float*)d_in[8],  *bs1 = (const float*)d_in[9];
    const float* Wq2 = (const float*)d_in[10], *bq2 = (const float*)d_in[11];
    const float* Wk2 = (const float*)d_in[12], *bk2 = (const float*)d_in[13];
    const float* Wv2 = (const float*)d_in[14], *bv2 = (const float*)d_in[15];
    const float* Ws2 = (const float*)d_in[16], *bs2 = (const float*)d_in[17];
    float* out = (float*)d_out;

    // workspace layout (~171 MB)
    char* ws = (char*)d_ws;
    size_t off = 0;
    auto alloc = [&](size_t bytes) -> void* {
        void* p = ws + off;
        off = (off + bytes + 255) & ~(size_t)255;
        return p;
    };
    unsigned short* Xb = (unsigned short*)alloc((size_t)N * 64 * 2);
    unsigned char* Qb  = (unsigned char*)alloc(((size_t)N + 64) * 512);
    unsigned char* Kb  = (unsigned char*)alloc(((size_t)N + 64) * 256);
    unsigned char* Vb  = (unsigned char*)alloc(((size_t)N + 64) * 512);
    float* S           = (float*)alloc(((size_t)N + 64) * 64 * 4);
    unsigned short* Wt = (unsigned short*)alloc(2 * 53248 * 2);
    int* counts = (int*)alloc((size_t)N * 4);
    int* cursor = (int*)alloc((size_t)N * 4);
    int* offs   = (int*)alloc((size_t)N * 4);
    int* bsums  = (int*)alloc(1024 * 4);
    int* csr    = (int*)alloc((size_t)E * 4);
    (void)n_in; (void)out_size;
    if (off > ws_size) return;  // diagnostic: too-small ws -> zeros, not a fault

    int ebl = (E + 255) / 256;
    int nb_scan = (N + SCAN_CHUNK - 1) / SCAN_CHUNK;
    int row_bl = (N + 63) / 64;
    int attn_bl = (N + 3) / 4;
    int ncast4 = N * 16;
    int castBl = (ncast4 + 255) / 256;
    int zeroBl = (N + 255) / 256;

    k_setup<<<castBl + 416 + zeroBl, 256, 0, stream>>>(
        x, Xb, ncast4, Wq1, Wk1, Wv1, Ws1, Wq2, Wk2, Wv2, Ws2, Wt,
        counts, cursor, N, castBl);

    k_hist<<<ebl, 256, 0, stream>>>(dstp, E, counts);
    k_scan1<<<nb_scan, SCAN_B, 0, stream>>>(counts, N, offs, bsums);
    k_scan2<<<1, 256, 0, stream>>>(bsums, nb_scan);
    k_scatter<<<ebl, 256, 0, stream>>>(srcp, dstp, E, offs, bsums, cursor, csr);

    dim3 g4(row_bl, 4);
    // ---- layer 1 (h1 -> Xb bf16 directly) ----
    k_mfma_qkvs<<<g4, 256, 0, stream>>>(Xb, N, Wt, bq1, bk1, bv1, bs1, Qb, Kb, Vb, S);
    k_attn<<<attn_bl, 256, 0, stream>>>(Qb, Kb, Vb, S, offs, bsums, csr, out, Xb, N, E, 1);

    // ---- layer 2 ----
    k_mfma_qkvs<<<g4, 256, 0, stream>>>(Xb, N, Wt + 53248, bq2, bk2, bv2, bs2, Qb, Kb, Vb, S);
    k_attn<<<attn_bl, 256, 0, stream>>>(Qb, Kb, Vb, S, offs, bsums, csr, out, Xb, N, E, 0);
}

// Round 9
// 564.835 us; speedup vs baseline: 1.5656x; 1.0441x over previous
//
#include <hip/hip_runtime.h>
#include <hip/hip_fp16.h>
#include <math.h>

// Graph TransformerConv ×2 on MI355X. N=100k, E=800k, D=64, H=4, C=64.
//
// R9: R8 showed write BYTES don't bind; the scattered per-lane store PATTERN
// does (each instr touches 16 node-strided lines; all pipes idle at 110 us).
// Fix: wave-private LDS transpose (R7's dense stores) WITHOUT R7's occupancy
// collapse: Q/K/V all fp8 e4m3, S fp32 -> uniform 256 B/node rows; each wave
// stages its 16x256-B tile in 4.25 KB LDS (stride 272: 2-way-free banks),
// one barrier, flush as dense dwordx4 lines. 17 KB LDS/block -> ~8 blocks/CU.
// Attn: K+V gathers now 4 B/lane each (8 lines/edge vs 12), Q/S reads halve.
// 9 dispatches. Workspace ~130 MB (guarded).

typedef __attribute__((ext_vector_type(8))) short bf16x8;
typedef __attribute__((ext_vector_type(4))) float f32x4;
typedef __attribute__((ext_vector_type(2))) float f32x2;

__device__ inline unsigned short f2bf(float f) {
    unsigned int u = __float_as_uint(f);
    u = (u + 0x7fffu + ((u >> 16) & 1u)) >> 16;
    return (unsigned short)u;
}

// ---------------- fp8 e4m3 pack/unpack (HW on gfx950) ----------------
#if __has_builtin(__builtin_amdgcn_cvt_pk_fp8_f32) && __has_builtin(__builtin_amdgcn_cvt_pk_f32_fp8)
#define HW_FP8 1
#endif

#ifndef HW_FP8
__device__ inline unsigned int fp8_enc1(float f) {
    unsigned int u = __float_as_uint(f);
    unsigned int s = (u >> 24) & 0x80u;
    float a = fabsf(f);
    if (a >= 448.f) return s | 0x7Eu;
    if (a < 0.015625f) return s;
    unsigned int ua = __float_as_uint(a);
    unsigned int r = ua + 0x7FFFFu + ((ua >> 20) & 1u);
    int e = (int)((r >> 23) & 255u) - 120;
    unsigned int m = (r >> 20) & 7u;
    if (e < 1) return s;
    if (e > 15) return s | 0x7Eu;
    return s | (unsigned int)((e << 3) | m);
}
__device__ inline float fp8_dec1(unsigned int b) {
    unsigned int e = (b >> 3) & 15u, m = b & 7u;
    float v;
    if (e) v = __uint_as_float(((e + 120u) << 23) | (m << 20));
    else   v = (float)m * 0.001953125f;
    return (b & 0x80u) ? -v : v;
}
#endif

__device__ inline unsigned int fp8x4_pack(float f0, float f1, float f2, float f3) {
#ifdef HW_FP8
    int pk = __builtin_amdgcn_cvt_pk_fp8_f32(f0, f1, 0, false);
    pk = __builtin_amdgcn_cvt_pk_fp8_f32(f2, f3, pk, true);
    return (unsigned int)pk;
#else
    return fp8_enc1(f0) | (fp8_enc1(f1) << 8) | (fp8_enc1(f2) << 16) | (fp8_enc1(f3) << 24);
#endif
}

__device__ inline float4 fp8x4_unpack(unsigned int k) {
#ifdef HW_FP8
    f32x2 lo = __builtin_amdgcn_cvt_pk_f32_fp8((int)k, false);
    f32x2 hi = __builtin_amdgcn_cvt_pk_f32_fp8((int)k, true);
    return make_float4(lo[0], lo[1], hi[0], hi[1]);
#else
    return make_float4(fp8_dec1(k & 255u), fp8_dec1((k >> 8) & 255u),
                       fp8_dec1((k >> 16) & 255u), fp8_dec1(k >> 24));
#endif
}

// ---------------- setup: X cast + weight prep (both layers) + CSR zero -----
__global__ void k_setup(
    const float* __restrict__ x, unsigned short* __restrict__ Xb, int ncast4,
    const float* __restrict__ Wq1, const float* __restrict__ Wk1,
    const float* __restrict__ Wv1, const float* __restrict__ Ws1,
    const float* __restrict__ Wq2, const float* __restrict__ Wk2,
    const float* __restrict__ Wv2, const float* __restrict__ Ws2,
    unsigned short* __restrict__ Wt,
    int* __restrict__ counts, int* __restrict__ cursor, int N, int castBl)
{
    int b = blockIdx.x, tid = threadIdx.x;
    if (b < castBl) {
        int i = b * 256 + tid;
        if (i < ncast4) {
            float4 v = ((const float4*)x)[i];
            ushort4 o;
            o.x = f2bf(v.x); o.y = f2bf(v.y); o.z = f2bf(v.z); o.w = f2bf(v.w);
            ((ushort4*)Xb)[i] = o;
        }
    } else if (b < castBl + 416) {
        int j = (b - castBl) * 256 + tid;   // < 106496
        int layer = j / 53248;
        int r = j % 53248;
        if (r < 49152) {
            int m = r / 16384, w = r % 16384;
            int n = w / 64, k = w % 64;
            const float* W = (layer == 0)
                ? ((m == 0) ? Wq1 : (m == 1) ? Wk1 : Wv1)
                : ((m == 0) ? Wq2 : (m == 1) ? Wk2 : Wv2);
            Wt[layer * 53248 + m * 16384 + n * 64 + k] = f2bf(W[k * 256 + n]);
        } else {
            int w = r - 49152;
            int n = w / 64, k = w % 64;
            const float* W = (layer == 0) ? Ws1 : Ws2;
            Wt[layer * 53248 + 49152 + n * 64 + k] = f2bf(W[k * 64 + n]);
        }
    } else {
        int i = (b - castBl - 416) * 256 + tid;
        if (i < N) { counts[i] = 0; cursor[i] = 0; }
    }
}

// ---------------- CSR build ----------------
__global__ void k_hist(const int* __restrict__ dst, int E, int* __restrict__ counts) {
    int e = blockIdx.x * 256 + threadIdx.x;
    if (e < E) atomicAdd(&counts[dst[e]], 1);
}

#define SCAN_B 256
#define SCAN_CHUNK 2048
__global__ void k_scan1(const int* __restrict__ counts, int n,
                        int* __restrict__ offs, int* __restrict__ bsums) {
    __shared__ int lds[SCAN_B];
    int b = blockIdx.x, tid = threadIdx.x;
    int base = b * SCAN_CHUNK + tid * 8;
    int v[8]; int s = 0;
#pragma unroll
    for (int i = 0; i < 8; ++i) { int idx = base + i; int c = (idx < n) ? counts[idx] : 0; v[i] = s; s += c; }
    lds[tid] = s;
    for (int off = 1; off < SCAN_B; off <<= 1) {
        __syncthreads();
        int x = (tid >= off) ? lds[tid - off] : 0;
        __syncthreads();
        lds[tid] += x;
    }
    __syncthreads();
    int texcl = lds[tid] - s;
#pragma unroll
    for (int i = 0; i < 8; ++i) { int idx = base + i; if (idx < n) offs[idx] = texcl + v[i]; }
    if (tid == SCAN_B - 1) bsums[b] = lds[tid];
}

__global__ void k_scan2(int* bsums, int nb) {
    __shared__ int lds[256];
    int t = threadIdx.x;
    if (nb > 256) {
        if (t == 0) { int s = 0; for (int i = 0; i < nb; ++i) { int c = bsums[i]; bsums[i] = s; s += c; } }
        return;
    }
    int v = (t < nb) ? bsums[t] : 0;
    lds[t] = v;
    for (int off = 1; off < 256; off <<= 1) {
        __syncthreads();
        int x = (t >= off) ? lds[t - off] : 0;
        __syncthreads();
        lds[t] += x;
    }
    __syncthreads();
    if (t < nb) bsums[t] = lds[t] - v;   // exclusive
}

__global__ void k_scatter(const int* __restrict__ src, const int* __restrict__ dst, int E,
                          const int* __restrict__ offs, const int* __restrict__ bsums,
                          int* __restrict__ cursor, int* __restrict__ csr_src) {
    int e = blockIdx.x * 256 + threadIdx.x;
    if (e < E) {
        int d = dst[e];
        int p = offs[d] + bsums[d >> 11] + atomicAdd(&cursor[d], 1);
        csr_src[p] = src[e];
    }
}

// ---------------- fused MFMA GEMM with wave-private LDS transpose ----------
// Operand-swapped mfma: D col=node (n16), row=channel (quad*4+reg).
// y=0/1/2: Q/K/V fp8 [node][256ch] = 256 B/row. y=3: S fp32 [node][64ch]
// = 256 B/row. Each wave stages its 16-node tile (4 KB, stride 272) in
// private LDS, then flushes 4x dense 1-KB dwordx4 spans (full 64-B lines).
#define TSTR 272
__global__ __launch_bounds__(256) void k_mfma_qkvs(
    const unsigned short* __restrict__ Xb, int nrows,
    const unsigned short* __restrict__ WtL,
    const float* __restrict__ bq, const float* __restrict__ bk,
    const float* __restrict__ bv, const float* __restrict__ bs,
    unsigned char* __restrict__ Qb, unsigned char* __restrict__ Kb,
    unsigned char* __restrict__ Vb, unsigned char* __restrict__ Sb)
{
    __shared__ char lds[4 * 16 * TSTR];   // 17408 B
    int mat = blockIdx.y;
    const unsigned short* Wt = WtL + ((mat < 3) ? mat * 16384 : 49152);
    const float* bias = (mat == 0) ? bq : (mat == 1) ? bk : (mat == 2) ? bv : bs;
    unsigned char* Ob = (mat == 0) ? Qb : (mat == 1) ? Kb : (mat == 2) ? Vb : Sb;
    int nct = (mat == 3) ? 4 : 16;
    int wave = threadIdx.x >> 6, lane = threadIdx.x & 63;
    int quad = lane >> 4, n16 = lane & 15;
    char* wlds = lds + wave * 16 * TSTR;
    int r0 = blockIdx.x * 64 + wave * 16;
    int arow = r0 + n16;
    int arowc = (arow < nrows) ? arow : (nrows - 1);
    bf16x8 a0 = *(const bf16x8*)(Xb + (size_t)arowc * 64 + quad * 8);
    bf16x8 a1 = *(const bf16x8*)(Xb + (size_t)arowc * 64 + 32 + quad * 8);
    for (int ct = 0; ct < nct; ++ct) {
        const unsigned short* wrow = Wt + (ct * 16 + n16) * 64;
        bf16x8 b0 = *(const bf16x8*)(wrow + quad * 8);
        bf16x8 b1 = *(const bf16x8*)(wrow + 32 + quad * 8);
        f32x4 acc = {0.f, 0.f, 0.f, 0.f};
        acc = __builtin_amdgcn_mfma_f32_16x16x32_bf16(b0, a0, acc, 0, 0, 0);
        acc = __builtin_amdgcn_mfma_f32_16x16x32_bf16(b1, a1, acc, 0, 0, 0);
        int ch0 = ct * 16 + quad * 4;
        float4 bb = *(const float4*)(bias + ch0);
        float f0 = acc[0] + bb.x, f1 = acc[1] + bb.y;
        float f2 = acc[2] + bb.z, f3 = acc[3] + bb.w;
        if (mat < 3) {
            *(unsigned int*)(wlds + n16 * TSTR + ct * 16 + quad * 4) =
                fp8x4_pack(f0, f1, f2, f3);
        } else {
            *(float4*)(wlds + n16 * TSTR + ct * 64 + quad * 16) =
                make_float4(f0, f1, f2, f3);
        }
    }
    __syncthreads();
#pragma unroll
    for (int it = 0; it < 4; ++it) {
        int g = it * 1024 + lane * 16;
        int row = g >> 8, off = g & 255;
        uint4 v = *(const uint4*)(wlds + row * TSTR + off);
        *(uint4*)(Ob + ((size_t)r0 + row) * 256 + off) = v;   // dense full lines
    }
}

// ---------------- Attention: one wave per dst node, no-max softmax ---------
__global__ __launch_bounds__(256) void k_attn(
    const unsigned char* __restrict__ Qb, const unsigned char* __restrict__ Kb,
    const unsigned char* __restrict__ Vb, const unsigned char* __restrict__ Sb,
    const int* __restrict__ offs, const int* __restrict__ bsums,
    const int* __restrict__ csr_src,
    float* __restrict__ out, unsigned short* __restrict__ Xb,
    int n, int Etot, int mode)
{
    int node = blockIdx.x * 4 + (threadIdx.x >> 6);
    if (node >= n) return;
    int lane = threadIdx.x & 63;
    int li = lane & 15;
    unsigned int qw = *(const unsigned int*)(Qb + (size_t)node * 256 + lane * 4);
    float4 qf = fp8x4_unpack(qw);
    float4 q = make_float4(qf.x * 0.125f, qf.y * 0.125f, qf.z * 0.125f, qf.w * 0.125f);
    int beg = offs[node] + bsums[node >> 11];
    int end = (node + 1 < n) ? (offs[node + 1] + bsums[(node + 1) >> 11]) : Etot;
    float l = 0.f;
    float4 acc = make_float4(0.f, 0.f, 0.f, 0.f);
    for (int base = beg; base < end; base += 8) {
        int cnt = end - base; if (cnt > 8) cnt = 8;
        int my = (lane < cnt) ? csr_src[base + lane] : 0;
        unsigned int kk[8], vv[8];
#pragma unroll
        for (int j = 0; j < 8; ++j) {
            int idx = __shfl(my, j);
            kk[j] = *(const unsigned int*)(Kb + (size_t)idx * 256 + lane * 4);
            vv[j] = *(const unsigned int*)(Vb + (size_t)idx * 256 + lane * 4);
        }
#pragma unroll
        for (int j = 0; j < 8; ++j) {
            float4 k4 = fp8x4_unpack(kk[j]);
            float d = q.x * k4.x + q.y * k4.y + q.z * k4.z + q.w * k4.w;
            d += __shfl_xor(d, 1); d += __shfl_xor(d, 2);
            d += __shfl_xor(d, 4); d += __shfl_xor(d, 8);
            float w = (j < cnt) ? __expf(d) : 0.f;
            l += w;
            float4 v4 = fp8x4_unpack(vv[j]);
            acc.x += v4.x * w; acc.y += v4.y * w;
            acc.z += v4.z * w; acc.w += v4.w * w;
        }
    }
    float inv = 1.f / (l + 1e-16f);
    float4 r = make_float4(acc.x * inv, acc.y * inv, acc.z * inv, acc.w * inv);
    r.x += __shfl_xor(r.x, 16); r.x += __shfl_xor(r.x, 32);
    r.y += __shfl_xor(r.y, 16); r.y += __shfl_xor(r.y, 32);
    r.z += __shfl_xor(r.z, 16); r.z += __shfl_xor(r.z, 32);
    r.w += __shfl_xor(r.w, 16); r.w += __shfl_xor(r.w, 32);
    float4 s4 = *(const float4*)(Sb + (size_t)node * 256 + li * 16);
    r.x = r.x * 0.25f + s4.x; r.y = r.y * 0.25f + s4.y;
    r.z = r.z * 0.25f + s4.z; r.w = r.w * 0.25f + s4.w;
    if (mode == 1) {
        if (lane < 16) {
            ushort4 o;
            o.x = f2bf(fmaxf(r.x, 0.f)); o.y = f2bf(fmaxf(r.y, 0.f));
            o.z = f2bf(fmaxf(r.z, 0.f)); o.w = f2bf(fmaxf(r.w, 0.f));
            ((ushort4*)(Xb + (size_t)node * 64))[li] = o;
        }
    } else {
        if (lane < 16) *(float4*)(out + (size_t)node * 64 + li * 4) = r;
    }
}

extern "C" void kernel_launch(void* const* d_in, const int* in_sizes, int n_in,
                              void* d_out, int out_size, void* d_ws, size_t ws_size,
                              hipStream_t stream)
{
    const float* x  = (const float*)d_in[0];
    const int*   ei = (const int*)d_in[1];
    int N = in_sizes[0] / 64;
    int E = in_sizes[1] / 2;
    const int* srcp = ei;
    const int* dstp = ei + E;
    const float* Wq1 = (const float*)d_in[2],  *bq1 = (const float*)d_in[3];
    const float* Wk1 = (const float*)d_in[4],  *bk1 = (const float*)d_in[5];
    const float* Wv1 = (const float*)d_in[6],  *bv1 = (const float*)d_in[7];
    const float* Ws1 = (const float*)d_in[8],  *bs1 = (const float*)d_in[9];
    const float* Wq2 = (const float*)d_in[10], *bq2 = (const float*)d_in[11];
    const float* Wk2 = (const float*)d_in[12], *bk2 = (const float*)d_in[13];
    const float* Wv2 = (const float*)d_in[14], *bv2 = (const float*)d_in[15];
    const float* Ws2 = (const float*)d_in[16], *bs2 = (const float*)d_in[17];
    float* out = (float*)d_out;

    // workspace layout (~130 MB)
    char* ws = (char*)d_ws;
    size_t off = 0;
    auto alloc = [&](size_t bytes) -> void* {
        void* p = ws + off;
        off = (off + bytes + 255) & ~(size_t)255;
        return p;
    };
    unsigned short* Xb = (unsigned short*)alloc((size_t)N * 64 * 2);
    unsigned char* Qb  = (unsigned char*)alloc(((size_t)N + 64) * 256);
    unsigned char* Kb  = (unsigned char*)alloc(((size_t)N + 64) * 256);
    unsigned char* Vb  = (unsigned char*)alloc(((size_t)N + 64) * 256);
    unsigned char* Sb  = (unsigned char*)alloc(((size_t)N + 64) * 256);
    unsigned short* Wt = (unsigned short*)alloc(2 * 53248 * 2);
    int* counts = (int*)alloc((size_t)N * 4);
    int* cursor = (int*)alloc((size_t)N * 4);
    int* offs   = (int*)alloc((size_t)N * 4);
    int* bsums  = (int*)alloc(1024 * 4);
    int* csr    = (int*)alloc((size_t)E * 4);
    (void)n_in; (void)out_size;
    if (off > ws_size) return;  // diagnostic: too-small ws -> zeros, not a fault

    int ebl = (E + 255) / 256;
    int nb_scan = (N + SCAN_CHUNK - 1) / SCAN_CHUNK;
    int row_bl = (N + 63) / 64;
    int attn_bl = (N + 3) / 4;
    int ncast4 = N * 16;
    int castBl = (ncast4 + 255) / 256;
    int zeroBl = (N + 255) / 256;

    k_setup<<<castBl + 416 + zeroBl, 256, 0, stream>>>(
        x, Xb, ncast4, Wq1, Wk1, Wv1, Ws1, Wq2, Wk2, Wv2, Ws2, Wt,
        counts, cursor, N, castBl);

    k_hist<<<ebl, 256, 0, stream>>>(dstp, E, counts);
    k_scan1<<<nb_scan, SCAN_B, 0, stream>>>(counts, N, offs, bsums);
    k_scan2<<<1, 256, 0, stream>>>(bsums, nb_scan);
    k_scatter<<<ebl, 256, 0, stream>>>(srcp, dstp, E, offs, bsums, cursor, csr);

    dim3 g4(row_bl, 4);
    // ---- layer 1 (h1 -> Xb bf16 directly) ----
    k_mfma_qkvs<<<g4, 256, 0, stream>>>(Xb, N, Wt, bq1, bk1, bv1, bs1, Qb, Kb, Vb, Sb);
    k_attn<<<attn_bl, 256, 0, stream>>>(Qb, Kb, Vb, Sb, offs, bsums, csr, out, Xb, N, E, 1);

    // ---- layer 2 ----
    k_mfma_qkvs<<<g4, 256, 0, stream>>>(Xb, N, Wt + 53248, bq2, bk2, bv2, bs2, Qb, Kb, Vb, Sb);
    k_attn<<<attn_bl, 256, 0, stream>>>(Qb, Kb, Vb, Sb, offs, bsums, csr, out, Xb, N, E, 0);
}

// Round 10
// 469.355 us; speedup vs baseline: 1.8841x; 1.2034x over previous
//
#include <hip/hip_runtime.h>
#include <hip/hip_fp16.h>
#include <math.h>

// Graph TransformerConv ×2 on MI355X. N=100k, E=800k, D=64, H=4, C=64.
//
// R10: GEMM dur was invariant (110-116 us) across 4 store structures with
// all pipes idle and FETCH=25 MB -> limiter is the L1/TCP REQUEST RATE of
// the read path: every wave re-read the full 32 KB weight tile with
// 16-lines-per-instruction loads (~14M tag lookups total). Fix: stage Wt
// and the Xb tile in LDS once per block (dense coalesced, padded stride
// 144 B), waves split by channel quarter with B-fragments preloaded into
// registers; A-fragments via ds_read. Load-line-reqs ~2300 -> ~650/block.
// Stores stay R8-style direct (proven neutral). Math bit-identical to R9.
// 9 dispatches. Workspace ~130 MB (guarded).

typedef __attribute__((ext_vector_type(8))) short bf16x8;
typedef __attribute__((ext_vector_type(4))) float f32x4;
typedef __attribute__((ext_vector_type(2))) float f32x2;

__device__ inline unsigned short f2bf(float f) {
    unsigned int u = __float_as_uint(f);
    u = (u + 0x7fffu + ((u >> 16) & 1u)) >> 16;
    return (unsigned short)u;
}

// ---------------- fp8 e4m3 pack/unpack (HW on gfx950) ----------------
#if __has_builtin(__builtin_amdgcn_cvt_pk_fp8_f32) && __has_builtin(__builtin_amdgcn_cvt_pk_f32_fp8)
#define HW_FP8 1
#endif

#ifndef HW_FP8
__device__ inline unsigned int fp8_enc1(float f) {
    unsigned int u = __float_as_uint(f);
    unsigned int s = (u >> 24) & 0x80u;
    float a = fabsf(f);
    if (a >= 448.f) return s | 0x7Eu;
    if (a < 0.015625f) return s;
    unsigned int ua = __float_as_uint(a);
    unsigned int r = ua + 0x7FFFFu + ((ua >> 20) & 1u);
    int e = (int)((r >> 23) & 255u) - 120;
    unsigned int m = (r >> 20) & 7u;
    if (e < 1) return s;
    if (e > 15) return s | 0x7Eu;
    return s | (unsigned int)((e << 3) | m);
}
__device__ inline float fp8_dec1(unsigned int b) {
    unsigned int e = (b >> 3) & 15u, m = b & 7u;
    float v;
    if (e) v = __uint_as_float(((e + 120u) << 23) | (m << 20));
    else   v = (float)m * 0.001953125f;
    return (b & 0x80u) ? -v : v;
}
#endif

__device__ inline unsigned int fp8x4_pack(float f0, float f1, float f2, float f3) {
#ifdef HW_FP8
    int pk = __builtin_amdgcn_cvt_pk_fp8_f32(f0, f1, 0, false);
    pk = __builtin_amdgcn_cvt_pk_fp8_f32(f2, f3, pk, true);
    return (unsigned int)pk;
#else
    return fp8_enc1(f0) | (fp8_enc1(f1) << 8) | (fp8_enc1(f2) << 16) | (fp8_enc1(f3) << 24);
#endif
}

__device__ inline float4 fp8x4_unpack(unsigned int k) {
#ifdef HW_FP8
    f32x2 lo = __builtin_amdgcn_cvt_pk_f32_fp8((int)k, false);
    f32x2 hi = __builtin_amdgcn_cvt_pk_f32_fp8((int)k, true);
    return make_float4(lo[0], lo[1], hi[0], hi[1]);
#else
    return make_float4(fp8_dec1(k & 255u), fp8_dec1((k >> 8) & 255u),
                       fp8_dec1((k >> 16) & 255u), fp8_dec1(k >> 24));
#endif
}

// ---------------- setup: X cast + weight prep (both layers) + CSR zero -----
__global__ void k_setup(
    const float* __restrict__ x, unsigned short* __restrict__ Xb, int ncast4,
    const float* __restrict__ Wq1, const float* __restrict__ Wk1,
    const float* __restrict__ Wv1, const float* __restrict__ Ws1,
    const float* __restrict__ Wq2, const float* __restrict__ Wk2,
    const float* __restrict__ Wv2, const float* __restrict__ Ws2,
    unsigned short* __restrict__ Wt,
    int* __restrict__ counts, int* __restrict__ cursor, int N, int castBl)
{
    int b = blockIdx.x, tid = threadIdx.x;
    if (b < castBl) {
        int i = b * 256 + tid;
        if (i < ncast4) {
            float4 v = ((const float4*)x)[i];
            ushort4 o;
            o.x = f2bf(v.x); o.y = f2bf(v.y); o.z = f2bf(v.z); o.w = f2bf(v.w);
            ((ushort4*)Xb)[i] = o;
        }
    } else if (b < castBl + 416) {
        int j = (b - castBl) * 256 + tid;   // < 106496
        int layer = j / 53248;
        int r = j % 53248;
        if (r < 49152) {
            int m = r / 16384, w = r % 16384;
            int n = w / 64, k = w % 64;
            const float* W = (layer == 0)
                ? ((m == 0) ? Wq1 : (m == 1) ? Wk1 : Wv1)
                : ((m == 0) ? Wq2 : (m == 1) ? Wk2 : Wv2);
            Wt[layer * 53248 + m * 16384 + n * 64 + k] = f2bf(W[k * 256 + n]);
        } else {
            int w = r - 49152;
            int n = w / 64, k = w % 64;
            const float* W = (layer == 0) ? Ws1 : Ws2;
            Wt[layer * 53248 + 49152 + n * 64 + k] = f2bf(W[k * 64 + n]);
        }
    } else {
        int i = (b - castBl - 416) * 256 + tid;
        if (i < N) { counts[i] = 0; cursor[i] = 0; }
    }
}

// ---------------- CSR build ----------------
__global__ void k_hist(const int* __restrict__ dst, int E, int* __restrict__ counts) {
    int e = blockIdx.x * 256 + threadIdx.x;
    if (e < E) atomicAdd(&counts[dst[e]], 1);
}

#define SCAN_B 256
#define SCAN_CHUNK 2048
__global__ void k_scan1(const int* __restrict__ counts, int n,
                        int* __restrict__ offs, int* __restrict__ bsums) {
    __shared__ int lds[SCAN_B];
    int b = blockIdx.x, tid = threadIdx.x;
    int base = b * SCAN_CHUNK + tid * 8;
    int v[8]; int s = 0;
#pragma unroll
    for (int i = 0; i < 8; ++i) { int idx = base + i; int c = (idx < n) ? counts[idx] : 0; v[i] = s; s += c; }
    lds[tid] = s;
    for (int off = 1; off < SCAN_B; off <<= 1) {
        __syncthreads();
        int x = (tid >= off) ? lds[tid - off] : 0;
        __syncthreads();
        lds[tid] += x;
    }
    __syncthreads();
    int texcl = lds[tid] - s;
#pragma unroll
    for (int i = 0; i < 8; ++i) { int idx = base + i; if (idx < n) offs[idx] = texcl + v[i]; }
    if (tid == SCAN_B - 1) bsums[b] = lds[tid];
}

__global__ void k_scan2(int* bsums, int nb) {
    __shared__ int lds[256];
    int t = threadIdx.x;
    if (nb > 256) {
        if (t == 0) { int s = 0; for (int i = 0; i < nb; ++i) { int c = bsums[i]; bsums[i] = s; s += c; } }
        return;
    }
    int v = (t < nb) ? bsums[t] : 0;
    lds[t] = v;
    for (int off = 1; off < 256; off <<= 1) {
        __syncthreads();
        int x = (t >= off) ? lds[t - off] : 0;
        __syncthreads();
        lds[t] += x;
    }
    __syncthreads();
    if (t < nb) bsums[t] = lds[t] - v;   // exclusive
}

__global__ void k_scatter(const int* __restrict__ src, const int* __restrict__ dst, int E,
                          const int* __restrict__ offs, const int* __restrict__ bsums,
                          int* __restrict__ cursor, int* __restrict__ csr_src) {
    int e = blockIdx.x * 256 + threadIdx.x;
    if (e < E) {
        int d = dst[e];
        int p = offs[d] + bsums[d >> 11] + atomicAdd(&cursor[d], 1);
        csr_src[p] = src[e];
    }
}

// ---------------- fused MFMA GEMM: LDS-resident Wt + Xb tile ---------------
// Block = 64 nodes x one mat (y=0..3). Staging: Wt rows (channel-major
// [n][k], 64 shorts) and Xb rows into LDS with stride 72 shorts (144 B,
// 16B-aligned, ~2-way banks). Waves split by channel quarter: wave w owns
// cts 4w..4w+3 (mat3: ct w), preloads its 8 B-fragments to registers, then
// loops 4 node-groups: A-frags from LDS, 2 MFMA/ct, direct stores.
#define WSTR 72
__global__ __launch_bounds__(256) void k_mfma_qkvs(
    const unsigned short* __restrict__ Xb, int nrows,
    const unsigned short* __restrict__ WtL,
    const float* __restrict__ bq, const float* __restrict__ bk,
    const float* __restrict__ bv, const float* __restrict__ bs,
    unsigned char* __restrict__ Qb, unsigned char* __restrict__ Kb,
    unsigned char* __restrict__ Vb, unsigned char* __restrict__ Sb)
{
    __shared__ short WtS[256 * WSTR];   // 36864 B
    __shared__ short XbS[64 * WSTR];    //  9216 B
    int mat = blockIdx.y;
    const unsigned short* Wt = WtL + ((mat < 3) ? mat * 16384 : 49152);
    const float* bias = (mat == 0) ? bq : (mat == 1) ? bk : (mat == 2) ? bv : bs;
    unsigned char* Ob = (mat == 0) ? Qb : (mat == 1) ? Kb : (mat == 2) ? Vb : Sb;
    int tid = threadIdx.x;
    int wave = tid >> 6, lane = tid & 63;
    int quad = lane >> 4, n16 = lane & 15;
    int r0 = blockIdx.x * 64;

    // ---- stage Wt (dense 16-B chunks; 8 chunks per 64-short row) ----
    int nrowsW = (mat < 3) ? 256 : 64;
    for (int c = tid; c < nrowsW * 8; c += 256) {
        int row = c >> 3, off = c & 7;
        uint4 v = *(const uint4*)(Wt + row * 64 + off * 8);
        *(uint4*)(&WtS[row * WSTR + off * 8]) = v;
    }
    // ---- stage Xb tile (64 rows, clamped) ----
    for (int c = tid; c < 64 * 8; c += 256) {
        int row = c >> 3, off = c & 7;
        int gr = r0 + row; if (gr >= nrows) gr = nrows - 1;
        uint4 v = *(const uint4*)(Xb + (size_t)gr * 64 + off * 8);
        *(uint4*)(&XbS[row * WSTR + off * 8]) = v;
    }
    __syncthreads();

    // ---- per-wave channel quarter ----
    int ncpw = (mat < 3) ? 4 : 1;
    int ctbase = (mat < 3) ? wave * 4 : wave;
    bf16x8 bf[8];
    float4 bb[4];
#pragma unroll
    for (int c = 0; c < 4; ++c) {
        if (c < ncpw) {
            int ct = ctbase + c;
            const short* wrow = &WtS[(ct * 16 + n16) * WSTR];
            bf[2 * c]     = *(const bf16x8*)(wrow + quad * 8);
            bf[2 * c + 1] = *(const bf16x8*)(wrow + 32 + quad * 8);
            bb[c] = *(const float4*)(bias + ct * 16 + quad * 4);
        }
    }
#pragma unroll
    for (int g = 0; g < 4; ++g) {
        const short* arow = &XbS[(g * 16 + n16) * WSTR];
        bf16x8 a0 = *(const bf16x8*)(arow + quad * 8);
        bf16x8 a1 = *(const bf16x8*)(arow + 32 + quad * 8);
        int node = r0 + g * 16 + n16;
        bool ok = node < nrows;
#pragma unroll
        for (int c = 0; c < 4; ++c) {
            if (c < ncpw) {
                f32x4 acc = {0.f, 0.f, 0.f, 0.f};
                acc = __builtin_amdgcn_mfma_f32_16x16x32_bf16(bf[2 * c], a0, acc, 0, 0, 0);
                acc = __builtin_amdgcn_mfma_f32_16x16x32_bf16(bf[2 * c + 1], a1, acc, 0, 0, 0);
                int ct = ctbase + c;
                int ch0 = ct * 16 + quad * 4;
                float f0 = acc[0] + bb[c].x, f1 = acc[1] + bb[c].y;
                float f2 = acc[2] + bb[c].z, f3 = acc[3] + bb[c].w;
                if (ok) {
                    if (mat < 3) {
                        *(unsigned int*)(Ob + (size_t)node * 256 + ch0) =
                            fp8x4_pack(f0, f1, f2, f3);
                    } else {
                        *(float4*)(Ob + (size_t)node * 256 + ch0 * 4) =
                            make_float4(f0, f1, f2, f3);
                    }
                }
            }
        }
    }
}

// ---------------- Attention: one wave per dst node, no-max softmax ---------
__global__ __launch_bounds__(256) void k_attn(
    const unsigned char* __restrict__ Qb, const unsigned char* __restrict__ Kb,
    const unsigned char* __restrict__ Vb, const unsigned char* __restrict__ Sb,
    const int* __restrict__ offs, const int* __restrict__ bsums,
    const int* __restrict__ csr_src,
    float* __restrict__ out, unsigned short* __restrict__ Xb,
    int n, int Etot, int mode)
{
    int node = blockIdx.x * 4 + (threadIdx.x >> 6);
    if (node >= n) return;
    int lane = threadIdx.x & 63;
    int li = lane & 15;
    unsigned int qw = *(const unsigned int*)(Qb + (size_t)node * 256 + lane * 4);
    float4 qf = fp8x4_unpack(qw);
    float4 q = make_float4(qf.x * 0.125f, qf.y * 0.125f, qf.z * 0.125f, qf.w * 0.125f);
    int beg = offs[node] + bsums[node >> 11];
    int end = (node + 1 < n) ? (offs[node + 1] + bsums[(node + 1) >> 11]) : Etot;
    float l = 0.f;
    float4 acc = make_float4(0.f, 0.f, 0.f, 0.f);
    for (int base = beg; base < end; base += 8) {
        int cnt = end - base; if (cnt > 8) cnt = 8;
        int my = (lane < cnt) ? csr_src[base + lane] : 0;
        unsigned int kk[8], vv[8];
#pragma unroll
        for (int j = 0; j < 8; ++j) {
            int idx = __shfl(my, j);
            kk[j] = *(const unsigned int*)(Kb + (size_t)idx * 256 + lane * 4);
            vv[j] = *(const unsigned int*)(Vb + (size_t)idx * 256 + lane * 4);
        }
#pragma unroll
        for (int j = 0; j < 8; ++j) {
            float4 k4 = fp8x4_unpack(kk[j]);
            float d = q.x * k4.x + q.y * k4.y + q.z * k4.z + q.w * k4.w;
            d += __shfl_xor(d, 1); d += __shfl_xor(d, 2);
            d += __shfl_xor(d, 4); d += __shfl_xor(d, 8);
            float w = (j < cnt) ? __expf(d) : 0.f;
            l += w;
            float4 v4 = fp8x4_unpack(vv[j]);
            acc.x += v4.x * w; acc.y += v4.y * w;
            acc.z += v4.z * w; acc.w += v4.w * w;
        }
    }
    float inv = 1.f / (l + 1e-16f);
    float4 r = make_float4(acc.x * inv, acc.y * inv, acc.z * inv, acc.w * inv);
    r.x += __shfl_xor(r.x, 16); r.x += __shfl_xor(r.x, 32);
    r.y += __shfl_xor(r.y, 16); r.y += __shfl_xor(r.y, 32);
    r.z += __shfl_xor(r.z, 16); r.z += __shfl_xor(r.z, 32);
    r.w += __shfl_xor(r.w, 16); r.w += __shfl_xor(r.w, 32);
    float4 s4 = *(const float4*)(Sb + (size_t)node * 256 + li * 16);
    r.x = r.x * 0.25f + s4.x; r.y = r.y * 0.25f + s4.y;
    r.z = r.z * 0.25f + s4.z; r.w = r.w * 0.25f + s4.w;
    if (mode == 1) {
        if (lane < 16) {
            ushort4 o;
            o.x = f2bf(fmaxf(r.x, 0.f)); o.y = f2bf(fmaxf(r.y, 0.f));
            o.z = f2bf(fmaxf(r.z, 0.f)); o.w = f2bf(fmaxf(r.w, 0.f));
            ((ushort4*)(Xb + (size_t)node * 64))[li] = o;
        }
    } else {
        if (lane < 16) *(float4*)(out + (size_t)node * 64 + li * 4) = r;
    }
}

extern "C" void kernel_launch(void* const* d_in, const int* in_sizes, int n_in,
                              void* d_out, int out_size, void* d_ws, size_t ws_size,
                              hipStream_t stream)
{
    const float* x  = (const float*)d_in[0];
    const int*   ei = (const int*)d_in[1];
    int N = in_sizes[0] / 64;
    int E = in_sizes[1] / 2;
    const int* srcp = ei;
    const int* dstp = ei + E;
    const float* Wq1 = (const float*)d_in[2],  *bq1 = (const float*)d_in[3];
    const float* Wk1 = (const float*)d_in[4],  *bk1 = (const float*)d_in[5];
    const float* Wv1 = (const float*)d_in[6],  *bv1 = (const float*)d_in[7];
    const float* Ws1 = (const float*)d_in[8],  *bs1 = (const float*)d_in[9];
    const float* Wq2 = (const float*)d_in[10], *bq2 = (const float*)d_in[11];
    const float* Wk2 = (const float*)d_in[12], *bk2 = (const float*)d_in[13];
    const float* Wv2 = (const float*)d_in[14], *bv2 = (const float*)d_in[15];
    const float* Ws2 = (const float*)d_in[16], *bs2 = (const float*)d_in[17];
    float* out = (float*)d_out;

    // workspace layout (~130 MB)
    char* ws = (char*)d_ws;
    size_t off = 0;
    auto alloc = [&](size_t bytes) -> void* {
        void* p = ws + off;
        off = (off + bytes + 255) & ~(size_t)255;
        return p;
    };
    unsigned short* Xb = (unsigned short*)alloc((size_t)N * 64 * 2);
    unsigned char* Qb  = (unsigned char*)alloc(((size_t)N + 64) * 256);
    unsigned char* Kb  = (unsigned char*)alloc(((size_t)N + 64) * 256);
    unsigned char* Vb  = (unsigned char*)alloc(((size_t)N + 64) * 256);
    unsigned char* Sb  = (unsigned char*)alloc(((size_t)N + 64) * 256);
    unsigned short* Wt = (unsigned short*)alloc(2 * 53248 * 2);
    int* counts = (int*)alloc((size_t)N * 4);
    int* cursor = (int*)alloc((size_t)N * 4);
    int* offs   = (int*)alloc((size_t)N * 4);
    int* bsums  = (int*)alloc(1024 * 4);
    int* csr    = (int*)alloc((size_t)E * 4);
    (void)n_in; (void)out_size;
    if (off > ws_size) return;  // diagnostic: too-small ws -> zeros, not a fault

    int ebl = (E + 255) / 256;
    int nb_scan = (N + SCAN_CHUNK - 1) / SCAN_CHUNK;
    int row_bl = (N + 63) / 64;
    int attn_bl = (N + 3) / 4;
    int ncast4 = N * 16;
    int castBl = (ncast4 + 255) / 256;
    int zeroBl = (N + 255) / 256;

    k_setup<<<castBl + 416 + zeroBl, 256, 0, stream>>>(
        x, Xb, ncast4, Wq1, Wk1, Wv1, Ws1, Wq2, Wk2, Wv2, Ws2, Wt,
        counts, cursor, N, castBl);

    k_hist<<<ebl, 256, 0, stream>>>(dstp, E, counts);
    k_scan1<<<nb_scan, SCAN_B, 0, stream>>>(counts, N, offs, bsums);
    k_scan2<<<1, 256, 0, stream>>>(bsums, nb_scan);
    k_scatter<<<ebl, 256, 0, stream>>>(srcp, dstp, E, offs, bsums, cursor, csr);

    dim3 g4(row_bl, 4);
    // ---- layer 1 (h1 -> Xb bf16 directly) ----
    k_mfma_qkvs<<<g4, 256, 0, stream>>>(Xb, N, Wt, bq1, bk1, bv1, bs1, Qb, Kb, Vb, Sb);
    k_attn<<<attn_bl, 256, 0, stream>>>(Qb, Kb, Vb, Sb, offs, bsums, csr, out, Xb, N, E, 1);

    // ---- layer 2 ----
    k_mfma_qkvs<<<g4, 256, 0, stream>>>(Xb, N, Wt + 53248, bq2, bk2, bv2, bs2, Qb, Kb, Vb, Sb);
    k_attn<<<attn_bl, 256, 0, stream>>>(Qb, Kb, Vb, Sb, offs, bsums, csr, out, Xb, N, E, 0);
}

// Round 11
// 447.242 us; speedup vs baseline: 1.9773x; 1.0494x over previous
//
#include <hip/hip_runtime.h>
#include <hip/hip_fp16.h>
#include <math.h>

// Graph TransformerConv ×2 on MI355X. N=100k, E=800k, D=64, H=4, C=64.
//
// R11: k_attn became VALU-issue-bound (77% VALUBusy, bytes L3-served).
// Cut per-edge VALU ~40%: (1) Q/K stored int8 (scale 32) -> 4-ch dot is one
// v_dot4_i32_i8, integer reduce, all scales folded into one mul before
// v_exp; (2) split-wave edge pairs: 32 lanes per edge, lane owns 8 channels
// of its head, reduce = 3 shfl_xor over 8 lanes, 2 edges in flight.
// V stays fp8, S fp32. GEMM packs Q/K int8 (idle VALU there).
// 11 dispatches. Workspace ~130 MB (guarded).

typedef __attribute__((ext_vector_type(8))) short bf16x8;
typedef __attribute__((ext_vector_type(4))) float f32x4;
typedef __attribute__((ext_vector_type(2))) float f32x2;

#define QKSCALE 32.0f
// logit = idot / (32*32*8); w = exp(logit) = exp2(idot * log2e/8192)
#define C_EXP2 1.760325e-4f

__device__ inline unsigned short f2bf(float f) {
    unsigned int u = __float_as_uint(f);
    u = (u + 0x7fffu + ((u >> 16) & 1u)) >> 16;
    return (unsigned short)u;
}

// ---------------- fp8 e4m3 pack/unpack (HW on gfx950) ----------------
#if __has_builtin(__builtin_amdgcn_cvt_pk_fp8_f32) && __has_builtin(__builtin_amdgcn_cvt_pk_f32_fp8)
#define HW_FP8 1
#endif

#ifndef HW_FP8
__device__ inline unsigned int fp8_enc1(float f) {
    unsigned int u = __float_as_uint(f);
    unsigned int s = (u >> 24) & 0x80u;
    float a = fabsf(f);
    if (a >= 448.f) return s | 0x7Eu;
    if (a < 0.015625f) return s;
    unsigned int ua = __float_as_uint(a);
    unsigned int r = ua + 0x7FFFFu + ((ua >> 20) & 1u);
    int e = (int)((r >> 23) & 255u) - 120;
    unsigned int m = (r >> 20) & 7u;
    if (e < 1) return s;
    if (e > 15) return s | 0x7Eu;
    return s | (unsigned int)((e << 3) | m);
}
__device__ inline float fp8_dec1(unsigned int b) {
    unsigned int e = (b >> 3) & 15u, m = b & 7u;
    float v;
    if (e) v = __uint_as_float(((e + 120u) << 23) | (m << 20));
    else   v = (float)m * 0.001953125f;
    return (b & 0x80u) ? -v : v;
}
#endif

__device__ inline unsigned int fp8x4_pack(float f0, float f1, float f2, float f3) {
#ifdef HW_FP8
    int pk = __builtin_amdgcn_cvt_pk_fp8_f32(f0, f1, 0, false);
    pk = __builtin_amdgcn_cvt_pk_fp8_f32(f2, f3, pk, true);
    return (unsigned int)pk;
#else
    return fp8_enc1(f0) | (fp8_enc1(f1) << 8) | (fp8_enc1(f2) << 16) | (fp8_enc1(f3) << 24);
#endif
}

__device__ inline float4 fp8x4_unpack(unsigned int k) {
#ifdef HW_FP8
    f32x2 lo = __builtin_amdgcn_cvt_pk_f32_fp8((int)k, false);
    f32x2 hi = __builtin_amdgcn_cvt_pk_f32_fp8((int)k, true);
    return make_float4(lo[0], lo[1], hi[0], hi[1]);
#else
    return make_float4(fp8_dec1(k & 255u), fp8_dec1((k >> 8) & 255u),
                       fp8_dec1((k >> 16) & 255u), fp8_dec1(k >> 24));
#endif
}

// ---------------- int8 pack / sdot4 ----------------
__device__ inline unsigned int i8x4_pack(float f0, float f1, float f2, float f3) {
    int a = (int)rintf(f0 * QKSCALE); a = a < -127 ? -127 : (a > 127 ? 127 : a);
    int b = (int)rintf(f1 * QKSCALE); b = b < -127 ? -127 : (b > 127 ? 127 : b);
    int c = (int)rintf(f2 * QKSCALE); c = c < -127 ? -127 : (c > 127 ? 127 : c);
    int d = (int)rintf(f3 * QKSCALE); d = d < -127 ? -127 : (d > 127 ? 127 : d);
    return (unsigned int)((a & 255) | ((b & 255) << 8) | ((c & 255) << 16) | ((d & 255) << 24));
}

__device__ inline int sdot4(unsigned int a, unsigned int b, int c) {
#if __has_builtin(__builtin_amdgcn_sdot4)
    return __builtin_amdgcn_sdot4((int)a, (int)b, c, false);
#else
    int r = c;
#pragma unroll
    for (int i = 0; i < 4; ++i) {
        int ai = (int)(a << (24 - 8 * i)) >> 24;
        int bi = (int)(b << (24 - 8 * i)) >> 24;
        r += ai * bi;
    }
    return r;
#endif
}

// ---------------- setup: X cast + weight prep (both layers) + CSR zero -----
__global__ void k_setup(
    const float* __restrict__ x, unsigned short* __restrict__ Xb, int ncast4,
    const float* __restrict__ Wq1, const float* __restrict__ Wk1,
    const float* __restrict__ Wv1, const float* __restrict__ Ws1,
    const float* __restrict__ Wq2, const float* __restrict__ Wk2,
    const float* __restrict__ Wv2, const float* __restrict__ Ws2,
    unsigned short* __restrict__ Wt,
    int* __restrict__ counts, int* __restrict__ cursor, int N, int castBl)
{
    int b = blockIdx.x, tid = threadIdx.x;
    if (b < castBl) {
        int i = b * 256 + tid;
        if (i < ncast4) {
            float4 v = ((const float4*)x)[i];
            ushort4 o;
            o.x = f2bf(v.x); o.y = f2bf(v.y); o.z = f2bf(v.z); o.w = f2bf(v.w);
            ((ushort4*)Xb)[i] = o;
        }
    } else if (b < castBl + 416) {
        int j = (b - castBl) * 256 + tid;   // < 106496
        int layer = j / 53248;
        int r = j % 53248;
        if (r < 49152) {
            int m = r / 16384, w = r % 16384;
            int n = w / 64, k = w % 64;
            const float* W = (layer == 0)
                ? ((m == 0) ? Wq1 : (m == 1) ? Wk1 : Wv1)
                : ((m == 0) ? Wq2 : (m == 1) ? Wk2 : Wv2);
            Wt[layer * 53248 + m * 16384 + n * 64 + k] = f2bf(W[k * 256 + n]);
        } else {
            int w = r - 49152;
            int n = w / 64, k = w % 64;
            const float* W = (layer == 0) ? Ws1 : Ws2;
            Wt[layer * 53248 + 49152 + n * 64 + k] = f2bf(W[k * 64 + n]);
        }
    } else {
        int i = (b - castBl - 416) * 256 + tid;
        if (i < N) { counts[i] = 0; cursor[i] = 0; }
    }
}

// ---------------- CSR build ----------------
__global__ void k_hist(const int* __restrict__ dst, int E, int* __restrict__ counts) {
    int e = blockIdx.x * 256 + threadIdx.x;
    if (e < E) atomicAdd(&counts[dst[e]], 1);
}

#define SCAN_B 256
#define SCAN_CHUNK 2048
__global__ void k_scan1(const int* __restrict__ counts, int n,
                        int* __restrict__ offs, int* __restrict__ bsums) {
    __shared__ int lds[SCAN_B];
    int b = blockIdx.x, tid = threadIdx.x;
    int base = b * SCAN_CHUNK + tid * 8;
    int v[8]; int s = 0;
#pragma unroll
    for (int i = 0; i < 8; ++i) { int idx = base + i; int c = (idx < n) ? counts[idx] : 0; v[i] = s; s += c; }
    lds[tid] = s;
    for (int off = 1; off < SCAN_B; off <<= 1) {
        __syncthreads();
        int x = (tid >= off) ? lds[tid - off] : 0;
        __syncthreads();
        lds[tid] += x;
    }
    __syncthreads();
    int texcl = lds[tid] - s;
#pragma unroll
    for (int i = 0; i < 8; ++i) { int idx = base + i; if (idx < n) offs[idx] = texcl + v[i]; }
    if (tid == SCAN_B - 1) bsums[b] = lds[tid];
}

__global__ void k_scan2(int* bsums, int nb) {
    __shared__ int lds[256];
    int t = threadIdx.x;
    if (nb > 256) {
        if (t == 0) { int s = 0; for (int i = 0; i < nb; ++i) { int c = bsums[i]; bsums[i] = s; s += c; } }
        return;
    }
    int v = (t < nb) ? bsums[t] : 0;
    lds[t] = v;
    for (int off = 1; off < 256; off <<= 1) {
        __syncthreads();
        int x = (t >= off) ? lds[t - off] : 0;
        __syncthreads();
        lds[t] += x;
    }
    __syncthreads();
    if (t < nb) bsums[t] = lds[t] - v;   // exclusive
}

__global__ void k_scatter(const int* __restrict__ src, const int* __restrict__ dst, int E,
                          const int* __restrict__ offs, const int* __restrict__ bsums,
                          int* __restrict__ cursor, int* __restrict__ csr_src) {
    int e = blockIdx.x * 256 + threadIdx.x;
    if (e < E) {
        int d = dst[e];
        int p = offs[d] + bsums[d >> 11] + atomicAdd(&cursor[d], 1);
        csr_src[p] = src[e];
    }
}

// ---------------- fused MFMA GEMM: LDS-resident Wt + Xb tile ---------------
// y=0: Q int8 [node][256]; y=1: K int8; y=2: V fp8; y=3: S fp32 [node][64].
#define WSTR 72
__global__ __launch_bounds__(256) void k_mfma_qkvs(
    const unsigned short* __restrict__ Xb, int nrows,
    const unsigned short* __restrict__ WtL,
    const float* __restrict__ bq, const float* __restrict__ bk,
    const float* __restrict__ bv, const float* __restrict__ bs,
    unsigned char* __restrict__ Qb, unsigned char* __restrict__ Kb,
    unsigned char* __restrict__ Vb, unsigned char* __restrict__ Sb)
{
    __shared__ short WtS[256 * WSTR];   // 36864 B
    __shared__ short XbS[64 * WSTR];    //  9216 B
    int mat = blockIdx.y;
    const unsigned short* Wt = WtL + ((mat < 3) ? mat * 16384 : 49152);
    const float* bias = (mat == 0) ? bq : (mat == 1) ? bk : (mat == 2) ? bv : bs;
    unsigned char* Ob = (mat == 0) ? Qb : (mat == 1) ? Kb : (mat == 2) ? Vb : Sb;
    int tid = threadIdx.x;
    int wave = tid >> 6, lane = tid & 63;
    int quad = lane >> 4, n16 = lane & 15;
    int r0 = blockIdx.x * 64;

    int nrowsW = (mat < 3) ? 256 : 64;
    for (int c = tid; c < nrowsW * 8; c += 256) {
        int row = c >> 3, off = c & 7;
        uint4 v = *(const uint4*)(Wt + row * 64 + off * 8);
        *(uint4*)(&WtS[row * WSTR + off * 8]) = v;
    }
    for (int c = tid; c < 64 * 8; c += 256) {
        int row = c >> 3, off = c & 7;
        int gr = r0 + row; if (gr >= nrows) gr = nrows - 1;
        uint4 v = *(const uint4*)(Xb + (size_t)gr * 64 + off * 8);
        *(uint4*)(&XbS[row * WSTR + off * 8]) = v;
    }
    __syncthreads();

    int ncpw = (mat < 3) ? 4 : 1;
    int ctbase = (mat < 3) ? wave * 4 : wave;
    bf16x8 bf[8];
    float4 bb[4];
#pragma unroll
    for (int c = 0; c < 4; ++c) {
        if (c < ncpw) {
            int ct = ctbase + c;
            const short* wrow = &WtS[(ct * 16 + n16) * WSTR];
            bf[2 * c]     = *(const bf16x8*)(wrow + quad * 8);
            bf[2 * c + 1] = *(const bf16x8*)(wrow + 32 + quad * 8);
            bb[c] = *(const float4*)(bias + ct * 16 + quad * 4);
        }
    }
#pragma unroll
    for (int g = 0; g < 4; ++g) {
        const short* arow = &XbS[(g * 16 + n16) * WSTR];
        bf16x8 a0 = *(const bf16x8*)(arow + quad * 8);
        bf16x8 a1 = *(const bf16x8*)(arow + 32 + quad * 8);
        int node = r0 + g * 16 + n16;
        bool ok = node < nrows;
#pragma unroll
        for (int c = 0; c < 4; ++c) {
            if (c < ncpw) {
                f32x4 acc = {0.f, 0.f, 0.f, 0.f};
                acc = __builtin_amdgcn_mfma_f32_16x16x32_bf16(bf[2 * c], a0, acc, 0, 0, 0);
                acc = __builtin_amdgcn_mfma_f32_16x16x32_bf16(bf[2 * c + 1], a1, acc, 0, 0, 0);
                int ct = ctbase + c;
                int ch0 = ct * 16 + quad * 4;
                float f0 = acc[0] + bb[c].x, f1 = acc[1] + bb[c].y;
                float f2 = acc[2] + bb[c].z, f3 = acc[3] + bb[c].w;
                if (ok) {
                    if (mat < 2) {
                        *(unsigned int*)(Ob + (size_t)node * 256 + ch0) =
                            i8x4_pack(f0, f1, f2, f3);
                    } else if (mat == 2) {
                        *(unsigned int*)(Ob + (size_t)node * 256 + ch0) =
                            fp8x4_pack(f0, f1, f2, f3);
                    } else {
                        *(float4*)(Ob + (size_t)node * 256 + ch0 * 4) =
                            make_float4(f0, f1, f2, f3);
                    }
                }
            }
        }
    }
}

// ---------------- Attention: split-wave edge pairs, int8 dot ---------------
// Half-wave (32 lanes) per edge; lane sl (0..31): head = sl>>3, owns 8
// channels sl*8..+8 of the 256-ch space. Reduce over 8 lanes (xor 1,2,4).
// Final: half-combine (xor32), head mean (xor8,16), lanes 0..7 write.
__global__ __launch_bounds__(256) void k_attn(
    const unsigned char* __restrict__ Qb, const unsigned char* __restrict__ Kb,
    const unsigned char* __restrict__ Vb, const unsigned char* __restrict__ Sb,
    const int* __restrict__ offs, const int* __restrict__ bsums,
    const int* __restrict__ csr_src,
    float* __restrict__ out, unsigned short* __restrict__ Xb,
    int n, int Etot, int mode)
{
    int node = blockIdx.x * 4 + (threadIdx.x >> 6);
    if (node >= n) return;
    int lane = threadIdx.x & 63;
    int sl = lane & 31;
    int half = lane >> 5;
    uint2 q8 = *(const uint2*)(Qb + (size_t)node * 256 + sl * 8);
    int beg = offs[node] + bsums[node >> 11];
    int end = (node + 1 < n) ? (offs[node + 1] + bsums[(node + 1) >> 11]) : Etot;
    float l = 0.f;
    float acc[8];
#pragma unroll
    for (int i = 0; i < 8; ++i) acc[i] = 0.f;
    for (int base = beg; base < end; base += 8) {
        int cnt = end - base; if (cnt > 8) cnt = 8;
        int my = (lane < cnt) ? csr_src[base + lane] : 0;
        uint2 kk[4], vv[4];
#pragma unroll
        for (int p = 0; p < 4; ++p) {
            int idx = __shfl(my, 2 * p + half);
            kk[p] = *(const uint2*)(Kb + (size_t)idx * 256 + sl * 8);
            vv[p] = *(const uint2*)(Vb + (size_t)idx * 256 + sl * 8);
        }
#pragma unroll
        for (int p = 0; p < 4; ++p) {
            int d = sdot4(kk[p].x, q8.x, 0);
            d = sdot4(kk[p].y, q8.y, d);
            d += __shfl_xor(d, 1); d += __shfl_xor(d, 2); d += __shfl_xor(d, 4);
            float w = __builtin_exp2f((float)d * C_EXP2);
            w = (2 * p + half < cnt) ? w : 0.f;
            l += w;
            float4 va = fp8x4_unpack(vv[p].x);
            float4 vb = fp8x4_unpack(vv[p].y);
            acc[0] += va.x * w; acc[1] += va.y * w;
            acc[2] += va.z * w; acc[3] += va.w * w;
            acc[4] += vb.x * w; acc[5] += vb.y * w;
            acc[6] += vb.z * w; acc[7] += vb.w * w;
        }
    }
    // combine halves (full edge set)
    l += __shfl_xor(l, 32);
#pragma unroll
    for (int i = 0; i < 8; ++i) acc[i] += __shfl_xor(acc[i], 32);
    // normalize per head
    float inv = 1.f / (l + 1e-16f);
#pragma unroll
    for (int i = 0; i < 8; ++i) acc[i] *= inv;
    // head mean: sum across head dim (bits 3,4 of sl), x0.25
#pragma unroll
    for (int i = 0; i < 8; ++i) {
        acc[i] += __shfl_xor(acc[i], 8);
        acc[i] += __shfl_xor(acc[i], 16);
        acc[i] *= 0.25f;
    }
    if (lane < 8) {
        // lane owns within-head channels lane*8..+8
        float4 s0 = *(const float4*)(Sb + (size_t)node * 256 + lane * 32);
        float4 s1 = *(const float4*)(Sb + (size_t)node * 256 + lane * 32 + 16);
        float r0 = acc[0] + s0.x, r1 = acc[1] + s0.y;
        float r2 = acc[2] + s0.z, r3 = acc[3] + s0.w;
        float r4 = acc[4] + s1.x, r5 = acc[5] + s1.y;
        float r6 = acc[6] + s1.z, r7 = acc[7] + s1.w;
        if (mode == 1) {
            r0 = fmaxf(r0, 0.f); r1 = fmaxf(r1, 0.f);
            r2 = fmaxf(r2, 0.f); r3 = fmaxf(r3, 0.f);
            r4 = fmaxf(r4, 0.f); r5 = fmaxf(r5, 0.f);
            r6 = fmaxf(r6, 0.f); r7 = fmaxf(r7, 0.f);
            uint4 o;
            o.x = (unsigned int)f2bf(r0) | ((unsigned int)f2bf(r1) << 16);
            o.y = (unsigned int)f2bf(r2) | ((unsigned int)f2bf(r3) << 16);
            o.z = (unsigned int)f2bf(r4) | ((unsigned int)f2bf(r5) << 16);
            o.w = (unsigned int)f2bf(r6) | ((unsigned int)f2bf(r7) << 16);
            *(uint4*)(Xb + (size_t)node * 64 + lane * 8) = o;
        } else {
            *(float4*)(out + (size_t)node * 64 + lane * 8) = make_float4(r0, r1, r2, r3);
            *(float4*)(out + (size_t)node * 64 + lane * 8 + 4) = make_float4(r4, r5, r6, r7);
        }
    }
}

extern "C" void kernel_launch(void* const* d_in, const int* in_sizes, int n_in,
                              void* d_out, int out_size, void* d_ws, size_t ws_size,
                              hipStream_t stream)
{
    const float* x  = (const float*)d_in[0];
    const int*   ei = (const int*)d_in[1];
    int N = in_sizes[0] / 64;
    int E = in_sizes[1] / 2;
    const int* srcp = ei;
    const int* dstp = ei + E;
    const float* Wq1 = (const float*)d_in[2],  *bq1 = (const float*)d_in[3];
    const float* Wk1 = (const float*)d_in[4],  *bk1 = (const float*)d_in[5];
    const float* Wv1 = (const float*)d_in[6],  *bv1 = (const float*)d_in[7];
    const float* Ws1 = (const float*)d_in[8],  *bs1 = (const float*)d_in[9];
    const float* Wq2 = (const float*)d_in[10], *bq2 = (const float*)d_in[11];
    const float* Wk2 = (const float*)d_in[12], *bk2 = (const float*)d_in[13];
    const float* Wv2 = (const float*)d_in[14], *bv2 = (const float*)d_in[15];
    const float* Ws2 = (const float*)d_in[16], *bs2 = (const float*)d_in[17];
    float* out = (float*)d_out;

    // workspace layout (~130 MB)
    char* ws = (char*)d_ws;
    size_t off = 0;
    auto alloc = [&](size_t bytes) -> void* {
        void* p = ws + off;
        off = (off + bytes + 255) & ~(size_t)255;
        return p;
    };
    unsigned short* Xb = (unsigned short*)alloc((size_t)N * 64 * 2);
    unsigned char* Qb  = (unsigned char*)alloc(((size_t)N + 64) * 256);
    unsigned char* Kb  = (unsigned char*)alloc(((size_t)N + 64) * 256);
    unsigned char* Vb  = (unsigned char*)alloc(((size_t)N + 64) * 256);
    unsigned char* Sb  = (unsigned char*)alloc(((size_t)N + 64) * 256);
    unsigned short* Wt = (unsigned short*)alloc(2 * 53248 * 2);
    int* counts = (int*)alloc((size_t)N * 4);
    int* cursor = (int*)alloc((size_t)N * 4);
    int* offs   = (int*)alloc((size_t)N * 4);
    int* bsums  = (int*)alloc(1024 * 4);
    int* csr    = (int*)alloc((size_t)E * 4);
    (void)n_in; (void)out_size;
    if (off > ws_size) return;  // diagnostic: too-small ws -> zeros, not a fault

    int ebl = (E + 255) / 256;
    int nb_scan = (N + SCAN_CHUNK - 1) / SCAN_CHUNK;
    int row_bl = (N + 63) / 64;
    int attn_bl = (N + 3) / 4;
    int ncast4 = N * 16;
    int castBl = (ncast4 + 255) / 256;
    int zeroBl = (N + 255) / 256;

    k_setup<<<castBl + 416 + zeroBl, 256, 0, stream>>>(
        x, Xb, ncast4, Wq1, Wk1, Wv1, Ws1, Wq2, Wk2, Wv2, Ws2, Wt,
        counts, cursor, N, castBl);

    k_hist<<<ebl, 256, 0, stream>>>(dstp, E, counts);
    k_scan1<<<nb_scan, SCAN_B, 0, stream>>>(counts, N, offs, bsums);
    k_scan2<<<1, 256, 0, stream>>>(bsums, nb_scan);
    k_scatter<<<ebl, 256, 0, stream>>>(srcp, dstp, E, offs, bsums, cursor, csr);

    dim3 g4(row_bl, 4);
    // ---- layer 1 (h1 -> Xb bf16 directly) ----
    k_mfma_qkvs<<<g4, 256, 0, stream>>>(Xb, N, Wt, bq1, bk1, bv1, bs1, Qb, Kb, Vb, Sb);
    k_attn<<<attn_bl, 256, 0, stream>>>(Qb, Kb, Vb, Sb, offs, bsums, csr, out, Xb, N, E, 1);

    // ---- layer 2 ----
    k_mfma_qkvs<<<g4, 256, 0, stream>>>(Xb, N, Wt + 53248, bq2, bk2, bv2, bs2, Qb, Kb, Vb, Sb);
    k_attn<<<attn_bl, 256, 0, stream>>>(Qb, Kb, Vb, Sb, offs, bsums, csr, out, Xb, N, E, 0);
}